// Round 6
// baseline (347.693 us; speedup 1.0000x reference)
//
#include <hip/hip_runtime.h>
#include <math.h>

#define NN 50000
#define NE 800000
#define DD 128
#define NBKT 196            // coarse buckets: row >> 8
#define BCAP 5120           // per-bucket capacity (mean 4082 -> 16-sigma margin)
#define CHUNK 2048          // edges per bin_kernel block
#define NCHUNK ((NE + CHUNK - 1) / CHUNK)   // 391
#define CS_NBLK 256         // colstats partial blocks

// ---------------- bf16 helpers (x stored as bf16 pairs packed in uint) ----------------
static __device__ __forceinline__ float blo(unsigned int p) { return __uint_as_float(p << 16); }
static __device__ __forceinline__ float bhi(unsigned int p) { return __uint_as_float(p & 0xffff0000u); }
static __device__ __forceinline__ unsigned int pack2bf(float a, float b) {
    unsigned int ua = __float_as_uint(a);
    unsigned int ub = __float_as_uint(b);
    ua = ua + 0x7FFFu + ((ua >> 16) & 1u);
    ub = ub + 0x7FFFu + ((ub >> 16) & 1u);
    return (ua >> 16) | (ub & 0xffff0000u);
}

// ---------------- pass 1: LDS counting-sort edges into 196 coarse buckets ----------------
// payload: uint2{ row | col<<16, val_bits }  (row, col < 65536)
static __global__ __launch_bounds__(256) void bin_kernel(
    const int* __restrict__ erow, const int* __restrict__ ecol, const float* __restrict__ eval_,
    int* __restrict__ bucket_cursor, uint2* __restrict__ binned) {
    __shared__ uint2 sorted[CHUNK];
    __shared__ unsigned short sbin[CHUNK];
    __shared__ int hist[NBKT];
    __shared__ int bstart[NBKT];
    __shared__ int bcur[NBKT];
    __shared__ int gbase[NBKT];
    __shared__ int tmp[256];

    int t = threadIdx.x;
    int cbase = blockIdx.x * CHUNK;
    int cn = NE - cbase; if (cn > CHUNK) cn = CHUNK;

    for (int i = t; i < NBKT; i += 256) hist[i] = 0;
    __syncthreads();

    unsigned int rc[8]; unsigned int vv[8]; int bb[8];
    int nloc = 0;
    for (int i = t; i < cn; i += 256) {
        int g = cbase + i;
        int r = erow[g];
        int c = ecol[g];
        float v = eval_[g];
        rc[nloc] = (unsigned)r | ((unsigned)c << 16);
        vv[nloc] = __float_as_uint(v);
        int b = r >> 8;
        bb[nloc] = b;
        atomicAdd(&hist[b], 1);
        ++nloc;
    }
    __syncthreads();

    // exclusive scan of hist -> bstart (256-thread Hillis-Steele)
    int hv = (t < NBKT) ? hist[t] : 0;
    tmp[t] = hv;
    __syncthreads();
    for (int off = 1; off < 256; off <<= 1) {
        int u = (t >= off) ? tmp[t - off] : 0;
        __syncthreads();
        tmp[t] += u;
        __syncthreads();
    }
    if (t < NBKT) {
        int ex = tmp[t] - hv;
        bstart[t] = ex;
        bcur[t] = ex;
        gbase[t] = atomicAdd(&bucket_cursor[t], hv);  // reserve contiguous run in bucket region
    }
    __syncthreads();

    // scatter into LDS (sorted by bucket)
    for (int k = 0; k < nloc; ++k) {
        int pos = atomicAdd(&bcur[bb[k]], 1);
        sorted[pos] = make_uint2(rc[k], vv[k]);
        sbin[pos] = (unsigned short)bb[k];
    }
    __syncthreads();

    // coalesced write-out: consecutive i in same bucket -> consecutive global slots
    for (int i = t; i < cn; i += 256) {
        int b = sbin[i];
        binned[(size_t)b * BCAP + gbase[b] + (i - bstart[b])] = sorted[i];
    }
}

// ---------------- exclusive scan of bucket totals ----------------
static __global__ void bucket_scan_kernel(const int* __restrict__ bucket_cursor,
                                          int* __restrict__ bucket_base) {
    __shared__ int tmp[256];
    int t = threadIdx.x;
    int v = (t < NBKT) ? bucket_cursor[t] : 0;
    tmp[t] = v;
    __syncthreads();
    for (int off = 1; off < 256; off <<= 1) {
        int u = (t >= off) ? tmp[t - off] : 0;
        __syncthreads();
        tmp[t] += u;
        __syncthreads();
    }
    if (t < NBKT) bucket_base[t] = tmp[t] - v;
}

// ---------------- pass 2: per-bucket sort by row -> final CSR + row_start ----------------
static __global__ __launch_bounds__(256) void sort_kernel(
    const uint2* __restrict__ binned, const int* __restrict__ bucket_cursor,
    const int* __restrict__ bucket_base, uint2* __restrict__ csr, int* __restrict__ row_start) {
    __shared__ uint2 buf[BCAP];
    __shared__ int hist[256];
    __shared__ int rcur[256];
    int b = blockIdx.x;
    int t = threadIdx.x;
    int cnt = bucket_cursor[b];
    int gb = bucket_base[b];
    int lo = b << 8;

    hist[t] = 0;
    __syncthreads();
    for (int i = t; i < cnt; i += 256) {
        uint2 e = binned[(size_t)b * BCAP + i];
        buf[i] = e;
        atomicAdd(&hist[(e.x & 0xFFFFu) - lo], 1);
    }
    __syncthreads();
    int hv = hist[t];
    rcur[t] = hv;  // inclusive-scan temp
    __syncthreads();
    for (int off = 1; off < 256; off <<= 1) {
        int u = (t >= off) ? rcur[t - off] : 0;
        __syncthreads();
        rcur[t] += u;
        __syncthreads();
    }
    int excl = rcur[t] - hv;
    int r = lo + t;
    if (r < NN) row_start[r] = gb + excl;
    if (b == NBKT - 1 && t == 255) row_start[NN] = gb + cnt;
    rcur[t] = excl;
    __syncthreads();
    for (int i = t; i < cnt; i += 256) {
        uint2 e = buf[i];
        int rr = (int)(e.x & 0xFFFFu) - lo;
        int pos = atomicAdd(&rcur[rr], 1);
        csr[(size_t)gb + pos] = make_uint2(e.x >> 16, e.y);
    }
}

// ---------------- degree from CSR row sums (no atomics), clamp zeros ----------------
static __global__ void deg_from_csr_kernel(const int* __restrict__ row_start,
                                           const uint2* __restrict__ csr,
                                           float* __restrict__ deg, int n) {
    int r = blockIdx.x * blockDim.x + threadIdx.x;
    if (r < n) {
        int s = row_start[r], e = row_start[r + 1];
        float sum = 0.0f;
        for (int j = s; j < e; ++j) sum += __uint_as_float(csr[j].y);
        deg[r] = (sum == 0.0f) ? 1.0f : sum;
    }
}

// x0 = R * deg^(-0.5), stored bf16-packed (one uint = 2 cols)
static __global__ void init_x_kernel(const float* __restrict__ R, const float* __restrict__ deg,
                                     unsigned int* __restrict__ xq, int npairs) {
    int i = blockIdx.x * blockDim.x + threadIdx.x;
    if (i < npairs) {
        float d = deg[i >> 6];  // 64 uints per row
        float sc = rsqrtf(d);
        float a = R[2 * i] * sc;
        float b = R[2 * i + 1] * sc;
        xq[i] = pack2bf(a, b);
    }
}

// ---------------- fused SpMM + inv_deg + row-normalize + weighted accumulate ----------------
// 256 threads = 4 waves per block; one wave per row.
// Wave split in halves: lanes 0-31 gather even neighbors, 32-63 odd neighbors;
// each lane loads uint2 (4 bf16 cols), so one load instruction = 2 neighbor rows.
static __global__ __launch_bounds__(256) void spmm_fused_kernel(
    const int* __restrict__ row_start, const uint2* __restrict__ csr,
    const uint2* __restrict__ x2, const float* __restrict__ deg,
    uint2* __restrict__ x_next2, float* __restrict__ acc, float weight, int overwrite) {
    int wave = threadIdx.x >> 6;
    int lane = threadIdx.x & 63;
    int half = lane >> 5;   // 0: even neighbors, 1: odd neighbors
    int sub  = lane & 31;   // column group: cols [4*sub, 4*sub+3]
    int row = blockIdx.x * 4 + wave;
    int s = row_start[row];
    int e = row_start[row + 1];

    float a0 = 0.f, a1 = 0.f, a2 = 0.f, a3 = 0.f;
    for (int base = s; base < e; base += 64) {
        int j = base + lane;
        int cl = 0;
        float vl = 0.0f;
        if (j < e) { uint2 t2 = csr[j]; cl = (int)t2.x; vl = __uint_as_float(t2.y); }
        int cnt = e - base; if (cnt > 64) cnt = 64;
        int k = 0;
        for (; k + 8 <= cnt; k += 8) {  // 8 neighbors per iter, 4 loads per lane in flight
            int c0 = __shfl(cl, k + half);
            int c1 = __shfl(cl, k + 2 + half);
            int c2 = __shfl(cl, k + 4 + half);
            int c3 = __shfl(cl, k + 6 + half);
            float v0 = __shfl(vl, k + half);
            float v1 = __shfl(vl, k + 2 + half);
            float v2 = __shfl(vl, k + 4 + half);
            float v3 = __shfl(vl, k + 6 + half);
            uint2 p0 = x2[(size_t)c0 * 32 + sub];
            uint2 p1 = x2[(size_t)c1 * 32 + sub];
            uint2 p2 = x2[(size_t)c2 * 32 + sub];
            uint2 p3 = x2[(size_t)c3 * 32 + sub];
            a0 += v0 * blo(p0.x); a1 += v0 * bhi(p0.x); a2 += v0 * blo(p0.y); a3 += v0 * bhi(p0.y);
            a0 += v1 * blo(p1.x); a1 += v1 * bhi(p1.x); a2 += v1 * blo(p1.y); a3 += v1 * bhi(p1.y);
            a0 += v2 * blo(p2.x); a1 += v2 * bhi(p2.x); a2 += v2 * blo(p2.y); a3 += v2 * bhi(p2.y);
            a0 += v3 * blo(p3.x); a1 += v3 * bhi(p3.x); a2 += v3 * blo(p3.y); a3 += v3 * bhi(p3.y);
        }
        for (; k < cnt; k += 2) {  // tail: 2 neighbors (one per half); kk<=63 since cnt<64 here
            int kk = k + half;     // lanes with kk >= cnt naturally see vl=0 from OOB lane init
            int c = __shfl(cl, kk);
            float v = __shfl(vl, kk);
            uint2 p = x2[(size_t)c * 32 + sub];
            a0 += v * blo(p.x); a1 += v * bhi(p.x); a2 += v * blo(p.y); a3 += v * bhi(p.y);
        }
    }
    // combine even/odd halves (both halves end with identical full sums)
    a0 += __shfl_xor(a0, 32);
    a1 += __shfl_xor(a1, 32);
    a2 += __shfl_xor(a2, 32);
    a3 += __shfl_xor(a3, 32);

    float id = 1.0f / deg[row];
    a0 *= id; a1 *= id; a2 *= id; a3 *= id;

    float ss = a0 * a0 + a1 * a1 + a2 * a2 + a3 * a3;
#pragma unroll
    for (int m = 1; m <= 16; m <<= 1) ss += __shfl_xor(ss, m);  // within-half; both halves identical
    float nrm = fmaxf(sqrtf(ss), 1e-12f);
    float w = weight / nrm;

    if (half == 0) {
        x_next2[(size_t)row * 32 + sub] = make_uint2(pack2bf(a0, a1), pack2bf(a2, a3));
        float4* acc4 = (float4*)acc;
        size_t idx = (size_t)row * 32 + sub;
        if (overwrite) {
            acc4[idx] = make_float4(a0 * w, a1 * w, a2 * w, a3 * w);
        } else {
            float4 p = acc4[idx];
            p.x += a0 * w; p.y += a1 * w; p.z += a2 * w; p.w += a3 * w;
            acc4[idx] = p;
        }
    }
}

// ---------------- column statistics: atomic-free two-pass ----------------
static __global__ void colstats_kernel(const float* __restrict__ acc,
                                       double* __restrict__ psum, double* __restrict__ psumsq) {
    int col = threadIdx.x;  // 0..127
    int b = blockIdx.x;
    double s = 0.0, q = 0.0;
    for (int r = b; r < NN; r += CS_NBLK) {
        float v = acc[(size_t)r * DD + col];
        s += (double)v;
        q += (double)v * (double)v;
    }
    psum[(size_t)b * DD + col] = s;
    psumsq[(size_t)b * DD + col] = q;
}

static __global__ void stats_kernel(const double* __restrict__ psum, const double* __restrict__ psumsq,
                                    float* __restrict__ mean, float* __restrict__ invstd) {
    int c = threadIdx.x;  // 128 threads
    double s = 0.0, q = 0.0;
    for (int b = 0; b < CS_NBLK; ++b) {
        s += psum[(size_t)b * DD + c];
        q += psumsq[(size_t)b * DD + c];
    }
    double m = s / (double)NN;
    double var = (q - (double)NN * m * m) / (double)(NN - 1);
    if (var < 0.0) var = 0.0;
    double sd = sqrt(var);
    if (sd == 0.0) sd = 1.0;
    mean[c] = (float)m;
    invstd[c] = (float)(1.0 / sd);
}

static __global__ void normalize_kernel(float* __restrict__ out, const float* __restrict__ mean,
                                        const float* __restrict__ invstd, int total) {
    int i = blockIdx.x * blockDim.x + threadIdx.x;
    if (i < total) {
        int c = i & 127;
        out[i] = (out[i] - mean[c]) * invstd[c];
    }
}

extern "C" void kernel_launch(void* const* d_in, const int* in_sizes, int n_in,
                              void* d_out, int out_size, void* d_ws, size_t ws_size,
                              hipStream_t stream) {
    const int* erow = (const int*)d_in[0];
    const int* ecol = (const int*)d_in[1];
    const float* eval_ = (const float*)d_in[2];
    const float* R = (const float*)d_in[3];
    float* out = (float*)d_out;  // acc lives here, normalized in place at the end

    // workspace layout
    char* ws = (char*)d_ws;
    size_t off = 0;
    auto alloc = [&](size_t bytes) -> char* {
        char* p = ws + off;
        off += (bytes + 255) & ~(size_t)255;
        return p;
    };
    float* deg          = (float*)alloc(NN * sizeof(float));
    int* bucket_cursor  = (int*)alloc(NBKT * sizeof(int));
    int* bucket_base    = (int*)alloc(NBKT * sizeof(int));
    int* row_start      = (int*)alloc((NN + 1) * sizeof(int));
    uint2* binned       = (uint2*)alloc((size_t)NBKT * BCAP * sizeof(uint2));
    uint2* csr          = (uint2*)alloc((size_t)NE * sizeof(uint2));
    uint2* x_a          = (uint2*)alloc((size_t)NN * 32 * sizeof(uint2));  // bf16 packed
    uint2* x_b          = (uint2*)alloc((size_t)NN * 32 * sizeof(uint2));
    double* psum        = (double*)alloc((size_t)CS_NBLK * DD * sizeof(double));
    double* psumsq      = (double*)alloc((size_t)CS_NBLK * DD * sizeof(double));
    float* meanbuf      = (float*)alloc(DD * sizeof(float));
    float* invstdb      = (float*)alloc(DD * sizeof(float));

    hipMemsetAsync(bucket_cursor, 0, NBKT * sizeof(int), stream);

    const int total = NN * DD;
    const int npairs = total / 2;

    bin_kernel<<<NCHUNK, 256, 0, stream>>>(erow, ecol, eval_, bucket_cursor, binned);
    bucket_scan_kernel<<<1, 256, 0, stream>>>(bucket_cursor, bucket_base);
    sort_kernel<<<NBKT, 256, 0, stream>>>(binned, bucket_cursor, bucket_base, csr, row_start);

    deg_from_csr_kernel<<<(NN + 255) / 256, 256, 0, stream>>>(row_start, csr, deg, NN);
    init_x_kernel<<<(npairs + 255) / 256, 256, 0, stream>>>(R, deg, (unsigned int*)x_a, npairs);

    const float weights[4] = {1.0f, 1.0f, 7.81f, 45.28f};
    uint2* xs[2] = {x_a, x_b};
    for (int i = 0; i < 4; ++i) {
        spmm_fused_kernel<<<NN / 4, 256, 0, stream>>>(row_start, csr,
                                                      xs[i & 1], deg, xs[(i + 1) & 1],
                                                      out, weights[i], i == 0 ? 1 : 0);
    }

    colstats_kernel<<<CS_NBLK, DD, 0, stream>>>(out, psum, psumsq);
    stats_kernel<<<1, DD, 0, stream>>>(psum, psumsq, meanbuf, invstdb);
    normalize_kernel<<<(total + 255) / 256, 256, 0, stream>>>(out, meanbuf, invstdb, total);
}

// Round 7
// 295.737 us; speedup vs baseline: 1.1757x; 1.1757x over previous
//
#include <hip/hip_runtime.h>
#include <math.h>

#define NN 50000
#define NE 800000
#define DD 128
#define NBKT 196            // coarse buckets: row >> 8
#define BCAP 5120           // per-bucket capacity (mean 4082 -> 16-sigma margin)
#define CHUNK 2048          // edges per bin_kernel block
#define NCHUNK ((NE + CHUNK - 1) / CHUNK)   // 391
#define CS1_NBLK 1024       // colstats pass-1 blocks
#define CS_ROWS 49          // rows per pass-1 block (1024*49 >= 50000)

// ---------------- bf16 helpers (x stored as bf16 pairs packed in uint) ----------------
static __device__ __forceinline__ float blo(unsigned int p) { return __uint_as_float(p << 16); }
static __device__ __forceinline__ float bhi(unsigned int p) { return __uint_as_float(p & 0xffff0000u); }
static __device__ __forceinline__ unsigned int pack2bf(float a, float b) {
    unsigned int ua = __float_as_uint(a);
    unsigned int ub = __float_as_uint(b);
    ua = ua + 0x7FFFu + ((ua >> 16) & 1u);
    ub = ub + 0x7FFFu + ((ub >> 16) & 1u);
    return (ua >> 16) | (ub & 0xffff0000u);
}

// ---------------- pass 1: LDS counting-sort edges into 196 coarse buckets ----------------
// payload: uint2{ row | col<<16, val_bits }  (row, col < 65536)
static __global__ __launch_bounds__(256) void bin_kernel(
    const int* __restrict__ erow, const int* __restrict__ ecol, const float* __restrict__ eval_,
    int* __restrict__ bucket_cursor, uint2* __restrict__ binned) {
    __shared__ uint2 sorted[CHUNK];
    __shared__ unsigned short sbin[CHUNK];
    __shared__ int hist[NBKT];
    __shared__ int bstart[NBKT];
    __shared__ int bcur[NBKT];
    __shared__ int gbase[NBKT];
    __shared__ int tmp[256];

    int t = threadIdx.x;
    int cbase = blockIdx.x * CHUNK;
    int cn = NE - cbase; if (cn > CHUNK) cn = CHUNK;

    for (int i = t; i < NBKT; i += 256) hist[i] = 0;
    __syncthreads();

    unsigned int rc[8]; unsigned int vv[8]; int bb[8];
    int nloc = 0;
    for (int i = t; i < cn; i += 256) {
        int g = cbase + i;
        int r = erow[g];
        int c = ecol[g];
        float v = eval_[g];
        rc[nloc] = (unsigned)r | ((unsigned)c << 16);
        vv[nloc] = __float_as_uint(v);
        int b = r >> 8;
        bb[nloc] = b;
        atomicAdd(&hist[b], 1);
        ++nloc;
    }
    __syncthreads();

    // exclusive scan of hist -> bstart (256-thread Hillis-Steele)
    int hv = (t < NBKT) ? hist[t] : 0;
    tmp[t] = hv;
    __syncthreads();
    for (int off = 1; off < 256; off <<= 1) {
        int u = (t >= off) ? tmp[t - off] : 0;
        __syncthreads();
        tmp[t] += u;
        __syncthreads();
    }
    if (t < NBKT) {
        int ex = tmp[t] - hv;
        bstart[t] = ex;
        bcur[t] = ex;
        gbase[t] = atomicAdd(&bucket_cursor[t], hv);  // reserve contiguous run in bucket region
    }
    __syncthreads();

    // scatter into LDS (sorted by bucket)
    for (int k = 0; k < nloc; ++k) {
        int pos = atomicAdd(&bcur[bb[k]], 1);
        sorted[pos] = make_uint2(rc[k], vv[k]);
        sbin[pos] = (unsigned short)bb[k];
    }
    __syncthreads();

    // coalesced write-out: consecutive i in same bucket -> consecutive global slots
    for (int i = t; i < cn; i += 256) {
        int b = sbin[i];
        binned[(size_t)b * BCAP + gbase[b] + (i - bstart[b])] = sorted[i];
    }
}

// ---------------- exclusive scan of bucket totals ----------------
static __global__ void bucket_scan_kernel(const int* __restrict__ bucket_cursor,
                                          int* __restrict__ bucket_base) {
    __shared__ int tmp[256];
    int t = threadIdx.x;
    int v = (t < NBKT) ? bucket_cursor[t] : 0;
    tmp[t] = v;
    __syncthreads();
    for (int off = 1; off < 256; off <<= 1) {
        int u = (t >= off) ? tmp[t - off] : 0;
        __syncthreads();
        tmp[t] += u;
        __syncthreads();
    }
    if (t < NBKT) bucket_base[t] = tmp[t] - v;
}

// ---------------- pass 2: per-bucket sort by row -> final CSR + row_start ----------------
static __global__ __launch_bounds__(256) void sort_kernel(
    const uint2* __restrict__ binned, const int* __restrict__ bucket_cursor,
    const int* __restrict__ bucket_base, uint2* __restrict__ csr, int* __restrict__ row_start) {
    __shared__ uint2 buf[BCAP];
    __shared__ int hist[256];
    __shared__ int rcur[256];
    int b = blockIdx.x;
    int t = threadIdx.x;
    int cnt = bucket_cursor[b];
    int gb = bucket_base[b];
    int lo = b << 8;

    hist[t] = 0;
    __syncthreads();
    for (int i = t; i < cnt; i += 256) {
        uint2 e = binned[(size_t)b * BCAP + i];
        buf[i] = e;
        atomicAdd(&hist[(e.x & 0xFFFFu) - lo], 1);
    }
    __syncthreads();
    int hv = hist[t];
    rcur[t] = hv;  // inclusive-scan temp
    __syncthreads();
    for (int off = 1; off < 256; off <<= 1) {
        int u = (t >= off) ? rcur[t - off] : 0;
        __syncthreads();
        rcur[t] += u;
        __syncthreads();
    }
    int excl = rcur[t] - hv;
    int r = lo + t;
    if (r < NN) row_start[r] = gb + excl;
    if (b == NBKT - 1 && t == 255) row_start[NN] = gb + cnt;
    rcur[t] = excl;
    __syncthreads();
    for (int i = t; i < cnt; i += 256) {
        uint2 e = buf[i];
        int rr = (int)(e.x & 0xFFFFu) - lo;
        int pos = atomicAdd(&rcur[rr], 1);
        csr[(size_t)gb + pos] = make_uint2(e.x >> 16, e.y);
    }
}

// ---------------- degree from CSR row sums (no atomics), clamp zeros ----------------
static __global__ void deg_from_csr_kernel(const int* __restrict__ row_start,
                                           const uint2* __restrict__ csr,
                                           float* __restrict__ deg, int n) {
    int r = blockIdx.x * blockDim.x + threadIdx.x;
    if (r < n) {
        int s = row_start[r], e = row_start[r + 1];
        float sum = 0.0f;
        for (int j = s; j < e; ++j) sum += __uint_as_float(csr[j].y);
        deg[r] = (sum == 0.0f) ? 1.0f : sum;
    }
}

// x0 = R * deg^(-0.5), stored bf16-packed (one uint = 2 cols)
static __global__ void init_x_kernel(const float* __restrict__ R, const float* __restrict__ deg,
                                     unsigned int* __restrict__ xq, int npairs) {
    int i = blockIdx.x * blockDim.x + threadIdx.x;
    if (i < npairs) {
        float d = deg[i >> 6];  // 64 uints per row
        float sc = rsqrtf(d);
        float a = R[2 * i] * sc;
        float b = R[2 * i + 1] * sc;
        xq[i] = pack2bf(a, b);
    }
}

// ---------------- fused SpMM + inv_deg + row-normalize + weighted accumulate ----------------
// 256 threads = 4 waves per block; one wave per row.
// Wave split in halves: lanes 0-31 gather even neighbors, 32-63 odd neighbors;
// each lane loads uint2 (4 bf16 cols), so one load instruction = 2 neighbor rows.
static __global__ __launch_bounds__(256) void spmm_fused_kernel(
    const int* __restrict__ row_start, const uint2* __restrict__ csr,
    const uint2* __restrict__ x2, const float* __restrict__ deg,
    uint2* __restrict__ x_next2, float* __restrict__ acc, float weight, int overwrite) {
    int wave = threadIdx.x >> 6;
    int lane = threadIdx.x & 63;
    int half = lane >> 5;   // 0: even neighbors, 1: odd neighbors
    int sub  = lane & 31;   // column group: cols [4*sub, 4*sub+3]
    int row = blockIdx.x * 4 + wave;
    int s = row_start[row];
    int e = row_start[row + 1];

    float a0 = 0.f, a1 = 0.f, a2 = 0.f, a3 = 0.f;
    for (int base = s; base < e; base += 64) {
        int j = base + lane;
        int cl = 0;
        float vl = 0.0f;
        if (j < e) { uint2 t2 = csr[j]; cl = (int)t2.x; vl = __uint_as_float(t2.y); }
        int cnt = e - base; if (cnt > 64) cnt = 64;
        int k = 0;
        for (; k + 8 <= cnt; k += 8) {  // 8 neighbors per iter, 4 loads per lane in flight
            int c0 = __shfl(cl, k + half);
            int c1 = __shfl(cl, k + 2 + half);
            int c2 = __shfl(cl, k + 4 + half);
            int c3 = __shfl(cl, k + 6 + half);
            float v0 = __shfl(vl, k + half);
            float v1 = __shfl(vl, k + 2 + half);
            float v2 = __shfl(vl, k + 4 + half);
            float v3 = __shfl(vl, k + 6 + half);
            uint2 p0 = x2[(size_t)c0 * 32 + sub];
            uint2 p1 = x2[(size_t)c1 * 32 + sub];
            uint2 p2 = x2[(size_t)c2 * 32 + sub];
            uint2 p3 = x2[(size_t)c3 * 32 + sub];
            a0 += v0 * blo(p0.x); a1 += v0 * bhi(p0.x); a2 += v0 * blo(p0.y); a3 += v0 * bhi(p0.y);
            a0 += v1 * blo(p1.x); a1 += v1 * bhi(p1.x); a2 += v1 * blo(p1.y); a3 += v1 * bhi(p1.y);
            a0 += v2 * blo(p2.x); a1 += v2 * bhi(p2.x); a2 += v2 * blo(p2.y); a3 += v2 * bhi(p2.y);
            a0 += v3 * blo(p3.x); a1 += v3 * bhi(p3.x); a2 += v3 * blo(p3.y); a3 += v3 * bhi(p3.y);
        }
        for (; k < cnt; k += 2) {  // tail: 2 neighbors (one per half)
            int kk = k + half;     // lanes with kk >= cnt naturally see vl=0 from OOB lane init
            int c = __shfl(cl, kk);
            float v = __shfl(vl, kk);
            uint2 p = x2[(size_t)c * 32 + sub];
            a0 += v * blo(p.x); a1 += v * bhi(p.x); a2 += v * blo(p.y); a3 += v * bhi(p.y);
        }
    }
    // combine even/odd halves (both halves end with identical full sums)
    a0 += __shfl_xor(a0, 32);
    a1 += __shfl_xor(a1, 32);
    a2 += __shfl_xor(a2, 32);
    a3 += __shfl_xor(a3, 32);

    float id = 1.0f / deg[row];
    a0 *= id; a1 *= id; a2 *= id; a3 *= id;

    float ss = a0 * a0 + a1 * a1 + a2 * a2 + a3 * a3;
#pragma unroll
    for (int m = 1; m <= 16; m <<= 1) ss += __shfl_xor(ss, m);  // within-half; both halves identical
    float nrm = fmaxf(sqrtf(ss), 1e-12f);
    float w = weight / nrm;

    if (half == 0) {
        x_next2[(size_t)row * 32 + sub] = make_uint2(pack2bf(a0, a1), pack2bf(a2, a3));
        float4* acc4 = (float4*)acc;
        size_t idx = (size_t)row * 32 + sub;
        if (overwrite) {
            acc4[idx] = make_float4(a0 * w, a1 * w, a2 * w, a3 * w);
        } else {
            float4 p = acc4[idx];
            p.x += a0 * w; p.y += a1 * w; p.z += a2 * w; p.w += a3 * w;
            acc4[idx] = p;
        }
    }
}

// ---------------- column statistics pass 1: per-block partials over contiguous row slab ----
// 1024 blocks x 256 threads (4 waves). Wave w takes rows rbeg+w, rbeg+w+4, ...
// Lane owns a float2 column pair. LDS-reduce the 4 waves, write 128-col partials.
static __global__ __launch_bounds__(256) void colstats_kernel(
    const float* __restrict__ acc, double* __restrict__ psum, double* __restrict__ psumsq) {
    __shared__ double shs[4 * 64 * 2];  // [wave][colpair][2]
    __shared__ double shq[4 * 64 * 2];
    int t = threadIdx.x;
    int wv = t >> 6;
    int cp = t & 63;
    int rbeg = blockIdx.x * CS_ROWS;
    int rend = rbeg + CS_ROWS; if (rend > NN) rend = NN;

    const float2* __restrict__ acc2 = (const float2*)acc;
    double s0 = 0.0, q0 = 0.0, s1 = 0.0, q1 = 0.0;
    for (int r = rbeg + wv; r < rend; r += 4) {
        float2 v = acc2[(size_t)r * 64 + cp];
        s0 += (double)v.x; q0 += (double)v.x * (double)v.x;
        s1 += (double)v.y; q1 += (double)v.y * (double)v.y;
    }
    shs[(wv * 64 + cp) * 2 + 0] = s0;
    shs[(wv * 64 + cp) * 2 + 1] = s1;
    shq[(wv * 64 + cp) * 2 + 0] = q0;
    shq[(wv * 64 + cp) * 2 + 1] = q1;
    __syncthreads();
    if (t < 128) {  // t = colpair*2 + half
        double s = shs[t] + shs[128 + t] + shs[256 + t] + shs[384 + t];
        double q = shq[t] + shq[128 + t] + shq[256 + t] + shq[384 + t];
        int col = (t >> 1) * 2 + (t & 1);  // == t
        psum[(size_t)blockIdx.x * DD + col] = s;
        psumsq[(size_t)blockIdx.x * DD + col] = q;
    }
}

// ---------------- pass 2: fold partials per column, compute mean/invstd ----------------
static __global__ __launch_bounds__(256) void colstats_fold_kernel(
    const double* __restrict__ psum, const double* __restrict__ psumsq,
    float* __restrict__ mean, float* __restrict__ invstd) {
    __shared__ double ss[256], qq[256];
    int c = blockIdx.x;   // 0..127
    int t = threadIdx.x;
    double s = 0.0, q = 0.0;
    for (int b = t; b < CS1_NBLK; b += 256) {
        s += psum[(size_t)b * DD + c];
        q += psumsq[(size_t)b * DD + c];
    }
    ss[t] = s; qq[t] = q;
    __syncthreads();
    for (int off = 128; off > 0; off >>= 1) {
        if (t < off) { ss[t] += ss[t + off]; qq[t] += qq[t + off]; }
        __syncthreads();
    }
    if (t == 0) {
        double m = ss[0] / (double)NN;
        double var = (qq[0] - (double)NN * m * m) / (double)(NN - 1);
        if (var < 0.0) var = 0.0;
        double sd = sqrt(var);
        if (sd == 0.0) sd = 1.0;
        mean[c] = (float)m;
        invstd[c] = (float)(1.0 / sd);
    }
}

static __global__ void normalize_kernel(float* __restrict__ out, const float* __restrict__ mean,
                                        const float* __restrict__ invstd, int total) {
    int i = blockIdx.x * blockDim.x + threadIdx.x;
    if (i < total) {
        int c = i & 127;
        out[i] = (out[i] - mean[c]) * invstd[c];
    }
}

extern "C" void kernel_launch(void* const* d_in, const int* in_sizes, int n_in,
                              void* d_out, int out_size, void* d_ws, size_t ws_size,
                              hipStream_t stream) {
    const int* erow = (const int*)d_in[0];
    const int* ecol = (const int*)d_in[1];
    const float* eval_ = (const float*)d_in[2];
    const float* R = (const float*)d_in[3];
    float* out = (float*)d_out;  // acc lives here, normalized in place at the end

    // workspace layout
    char* ws = (char*)d_ws;
    size_t off = 0;
    auto alloc = [&](size_t bytes) -> char* {
        char* p = ws + off;
        off += (bytes + 255) & ~(size_t)255;
        return p;
    };
    float* deg          = (float*)alloc(NN * sizeof(float));
    int* bucket_cursor  = (int*)alloc(NBKT * sizeof(int));
    int* bucket_base    = (int*)alloc(NBKT * sizeof(int));
    int* row_start      = (int*)alloc((NN + 1) * sizeof(int));
    uint2* binned       = (uint2*)alloc((size_t)NBKT * BCAP * sizeof(uint2));
    uint2* csr          = (uint2*)alloc((size_t)NE * sizeof(uint2));
    uint2* x_a          = (uint2*)alloc((size_t)NN * 32 * sizeof(uint2));  // bf16 packed
    uint2* x_b          = (uint2*)alloc((size_t)NN * 32 * sizeof(uint2));
    double* psum        = (double*)alloc((size_t)CS1_NBLK * DD * sizeof(double));
    double* psumsq      = (double*)alloc((size_t)CS1_NBLK * DD * sizeof(double));
    float* meanbuf      = (float*)alloc(DD * sizeof(float));
    float* invstdb      = (float*)alloc(DD * sizeof(float));

    hipMemsetAsync(bucket_cursor, 0, NBKT * sizeof(int), stream);

    const int total = NN * DD;
    const int npairs = total / 2;

    bin_kernel<<<NCHUNK, 256, 0, stream>>>(erow, ecol, eval_, bucket_cursor, binned);
    bucket_scan_kernel<<<1, 256, 0, stream>>>(bucket_cursor, bucket_base);
    sort_kernel<<<NBKT, 256, 0, stream>>>(binned, bucket_cursor, bucket_base, csr, row_start);

    deg_from_csr_kernel<<<(NN + 255) / 256, 256, 0, stream>>>(row_start, csr, deg, NN);
    init_x_kernel<<<(npairs + 255) / 256, 256, 0, stream>>>(R, deg, (unsigned int*)x_a, npairs);

    const float weights[4] = {1.0f, 1.0f, 7.81f, 45.28f};
    uint2* xs[2] = {x_a, x_b};
    for (int i = 0; i < 4; ++i) {
        spmm_fused_kernel<<<NN / 4, 256, 0, stream>>>(row_start, csr,
                                                      xs[i & 1], deg, xs[(i + 1) & 1],
                                                      out, weights[i], i == 0 ? 1 : 0);
    }

    colstats_kernel<<<CS1_NBLK, 256, 0, stream>>>(out, psum, psumsq);
    colstats_fold_kernel<<<DD, 256, 0, stream>>>(psum, psumsq, meanbuf, invstdb);
    normalize_kernel<<<(total + 255) / 256, 256, 0, stream>>>(out, meanbuf, invstdb, total);
}

// Round 8
// 273.652 us; speedup vs baseline: 1.2706x; 1.0807x over previous
//
#include <hip/hip_runtime.h>
#include <math.h>

#define NN 50000
#define NE 800000
#define DD 128
#define NBKT 196            // coarse buckets: row >> 8
#define BCAP 5120           // per-bucket capacity (mean 4082 -> 16-sigma margin)
#define CHUNK 2048          // edges per bin_kernel block
#define NCHUNK ((NE + CHUNK - 1) / CHUNK)   // 391
#define CS1_NBLK 1024       // combine/colstats pass-1 blocks
#define CS_ROWS 49          // rows per pass-1 block (1024*49 >= 50000)

// ---------------- bf16 helpers (x stored as bf16 pairs packed in uint) ----------------
static __device__ __forceinline__ float blo(unsigned int p) { return __uint_as_float(p << 16); }
static __device__ __forceinline__ float bhi(unsigned int p) { return __uint_as_float(p & 0xffff0000u); }
static __device__ __forceinline__ unsigned int pack2bf(float a, float b) {
    unsigned int ua = __float_as_uint(a);
    unsigned int ub = __float_as_uint(b);
    ua = ua + 0x7FFFu + ((ua >> 16) & 1u);
    ub = ub + 0x7FFFu + ((ub >> 16) & 1u);
    return (ua >> 16) | (ub & 0xffff0000u);
}

// ---------------- pass 1: LDS counting-sort edges into 196 coarse buckets ----------------
// payload: uint2{ row | col<<16, val_bits }  (row, col < 65536)
static __global__ __launch_bounds__(256) void bin_kernel(
    const int* __restrict__ erow, const int* __restrict__ ecol, const float* __restrict__ eval_,
    int* __restrict__ bucket_cursor, uint2* __restrict__ binned) {
    __shared__ uint2 sorted[CHUNK];
    __shared__ unsigned short sbin[CHUNK];
    __shared__ int hist[NBKT];
    __shared__ int bstart[NBKT];
    __shared__ int bcur[NBKT];
    __shared__ int gbase[NBKT];
    __shared__ int tmp[256];

    int t = threadIdx.x;
    int cbase = blockIdx.x * CHUNK;
    int cn = NE - cbase; if (cn > CHUNK) cn = CHUNK;

    for (int i = t; i < NBKT; i += 256) hist[i] = 0;
    __syncthreads();

    unsigned int rc[8]; unsigned int vv[8]; int bb[8];
    int nloc = 0;
    for (int i = t; i < cn; i += 256) {
        int g = cbase + i;
        int r = erow[g];
        int c = ecol[g];
        float v = eval_[g];
        rc[nloc] = (unsigned)r | ((unsigned)c << 16);
        vv[nloc] = __float_as_uint(v);
        int b = r >> 8;
        bb[nloc] = b;
        atomicAdd(&hist[b], 1);
        ++nloc;
    }
    __syncthreads();

    // exclusive scan of hist -> bstart (256-thread Hillis-Steele)
    int hv = (t < NBKT) ? hist[t] : 0;
    tmp[t] = hv;
    __syncthreads();
    for (int off = 1; off < 256; off <<= 1) {
        int u = (t >= off) ? tmp[t - off] : 0;
        __syncthreads();
        tmp[t] += u;
        __syncthreads();
    }
    if (t < NBKT) {
        int ex = tmp[t] - hv;
        bstart[t] = ex;
        bcur[t] = ex;
        gbase[t] = atomicAdd(&bucket_cursor[t], hv);  // reserve contiguous run in bucket region
    }
    __syncthreads();

    // scatter into LDS (sorted by bucket)
    for (int k = 0; k < nloc; ++k) {
        int pos = atomicAdd(&bcur[bb[k]], 1);
        sorted[pos] = make_uint2(rc[k], vv[k]);
        sbin[pos] = (unsigned short)bb[k];
    }
    __syncthreads();

    // coalesced write-out: consecutive i in same bucket -> consecutive global slots
    for (int i = t; i < cn; i += 256) {
        int b = sbin[i];
        binned[(size_t)b * BCAP + gbase[b] + (i - bstart[b])] = sorted[i];
    }
}

// ---------------- exclusive scan of bucket totals ----------------
static __global__ void bucket_scan_kernel(const int* __restrict__ bucket_cursor,
                                          int* __restrict__ bucket_base) {
    __shared__ int tmp[256];
    int t = threadIdx.x;
    int v = (t < NBKT) ? bucket_cursor[t] : 0;
    tmp[t] = v;
    __syncthreads();
    for (int off = 1; off < 256; off <<= 1) {
        int u = (t >= off) ? tmp[t - off] : 0;
        __syncthreads();
        tmp[t] += u;
        __syncthreads();
    }
    if (t < NBKT) bucket_base[t] = tmp[t] - v;
}

// ---------------- pass 2: per-bucket sort by row -> final CSR + row_start ----------------
static __global__ __launch_bounds__(256) void sort_kernel(
    const uint2* __restrict__ binned, const int* __restrict__ bucket_cursor,
    const int* __restrict__ bucket_base, uint2* __restrict__ csr, int* __restrict__ row_start) {
    __shared__ uint2 buf[BCAP];
    __shared__ int hist[256];
    __shared__ int rcur[256];
    int b = blockIdx.x;
    int t = threadIdx.x;
    int cnt = bucket_cursor[b];
    int gb = bucket_base[b];
    int lo = b << 8;

    hist[t] = 0;
    __syncthreads();
    for (int i = t; i < cnt; i += 256) {
        uint2 e = binned[(size_t)b * BCAP + i];
        buf[i] = e;
        atomicAdd(&hist[(e.x & 0xFFFFu) - lo], 1);
    }
    __syncthreads();
    int hv = hist[t];
    rcur[t] = hv;  // inclusive-scan temp
    __syncthreads();
    for (int off = 1; off < 256; off <<= 1) {
        int u = (t >= off) ? rcur[t - off] : 0;
        __syncthreads();
        rcur[t] += u;
        __syncthreads();
    }
    int excl = rcur[t] - hv;
    int r = lo + t;
    if (r < NN) row_start[r] = gb + excl;
    if (b == NBKT - 1 && t == 255) row_start[NN] = gb + cnt;
    rcur[t] = excl;
    __syncthreads();
    for (int i = t; i < cnt; i += 256) {
        uint2 e = buf[i];
        int rr = (int)(e.x & 0xFFFFu) - lo;
        int pos = atomicAdd(&rcur[rr], 1);
        csr[(size_t)gb + pos] = make_uint2(e.x >> 16, e.y);
    }
}

// ---------------- degree from CSR row sums (no atomics), clamp zeros ----------------
static __global__ void deg_from_csr_kernel(const int* __restrict__ row_start,
                                           const uint2* __restrict__ csr,
                                           float* __restrict__ deg, int n) {
    int r = blockIdx.x * blockDim.x + threadIdx.x;
    if (r < n) {
        int s = row_start[r], e = row_start[r + 1];
        float sum = 0.0f;
        for (int j = s; j < e; ++j) sum += __uint_as_float(csr[j].y);
        deg[r] = (sum == 0.0f) ? 1.0f : sum;
    }
}

// x0 = R * deg^(-0.5), stored bf16-packed as uint4 (8 cols per lane-slot)
static __global__ void init_x_kernel(const float* __restrict__ R, const float* __restrict__ deg,
                                     uint4* __restrict__ xq, int nquads) {
    int i = blockIdx.x * blockDim.x + threadIdx.x;
    if (i < nquads) {
        float d = deg[i >> 4];  // 16 uint4 per row
        float sc = rsqrtf(d);
        const float4* R4 = (const float4*)R;
        float4 f0 = R4[i * 2];
        float4 f1 = R4[i * 2 + 1];
        xq[i] = make_uint4(pack2bf(f0.x * sc, f0.y * sc), pack2bf(f0.z * sc, f0.w * sc),
                           pack2bf(f1.x * sc, f1.y * sc), pack2bf(f1.z * sc, f1.w * sc));
    }
}

// ---------------- fused SpMM + inv_deg + row-norm scalar ----------------
// 256 threads = 4 waves per block; one wave per row.
// Wave split in quarters: quarter q handles neighbors k+q; lane loads uint4
// (8 bf16 cols, 16 B) -> one load instruction gathers FOUR neighbor rows.
// No acc RMW: writes x_next (bf16) and per-row scalar s = weight/nrm.
static __global__ __launch_bounds__(256) void spmm_fused_kernel(
    const int* __restrict__ row_start, const uint2* __restrict__ csr,
    const uint4* __restrict__ x4, const float* __restrict__ deg,
    uint4* __restrict__ x_next4, float* __restrict__ s_out, float weight) {
    int wave = threadIdx.x >> 6;
    int lane = threadIdx.x & 63;
    int quarter = lane >> 4;  // 0..3
    int sub = lane & 15;      // col group: cols [8*sub, 8*sub+7]
    int row = blockIdx.x * 4 + wave;
    int s = row_start[row];
    int e = row_start[row + 1];

    float a0 = 0.f, a1 = 0.f, a2 = 0.f, a3 = 0.f, a4 = 0.f, a5 = 0.f, a6 = 0.f, a7 = 0.f;
    for (int base = s; base < e; base += 64) {
        int j = base + lane;
        int cl = 0;
        float vl = 0.0f;
        if (j < e) { uint2 t2 = csr[j]; cl = (int)t2.x; vl = __uint_as_float(t2.y); }
        int cnt = e - base; if (cnt > 64) cnt = 64;
        int k = 0;
        for (; k + 8 <= cnt; k += 8) {  // 8 neighbors/iter, 2 uint4 loads in flight per lane
            int ca = __shfl(cl, k + quarter);
            int cb = __shfl(cl, k + 4 + quarter);
            float va = __shfl(vl, k + quarter);
            float vb = __shfl(vl, k + 4 + quarter);
            uint4 pa = x4[(size_t)ca * 16 + sub];
            uint4 pb = x4[(size_t)cb * 16 + sub];
            a0 += va * blo(pa.x); a1 += va * bhi(pa.x); a2 += va * blo(pa.y); a3 += va * bhi(pa.y);
            a4 += va * blo(pa.z); a5 += va * bhi(pa.z); a6 += va * blo(pa.w); a7 += va * bhi(pa.w);
            a0 += vb * blo(pb.x); a1 += vb * bhi(pb.x); a2 += vb * blo(pb.y); a3 += vb * bhi(pb.y);
            a4 += vb * blo(pb.z); a5 += vb * bhi(pb.z); a6 += vb * blo(pb.w); a7 += vb * bhi(pb.w);
        }
        for (; k < cnt; k += 4) {   // tail: 4 neighbors; kk<=63 (k<=60, quarter<=3)
            int kk = k + quarter;   // lanes with kk>=cnt see cl=0, vl=0 -> contribute 0
            int c = __shfl(cl, kk);
            float v = __shfl(vl, kk);
            uint4 p = x4[(size_t)c * 16 + sub];
            a0 += v * blo(p.x); a1 += v * bhi(p.x); a2 += v * blo(p.y); a3 += v * bhi(p.y);
            a4 += v * blo(p.z); a5 += v * bhi(p.z); a6 += v * blo(p.w); a7 += v * bhi(p.w);
        }
    }
    // combine quarters (after this all lanes with same sub hold full sums)
    a0 += __shfl_xor(a0, 16); a1 += __shfl_xor(a1, 16); a2 += __shfl_xor(a2, 16); a3 += __shfl_xor(a3, 16);
    a4 += __shfl_xor(a4, 16); a5 += __shfl_xor(a5, 16); a6 += __shfl_xor(a6, 16); a7 += __shfl_xor(a7, 16);
    a0 += __shfl_xor(a0, 32); a1 += __shfl_xor(a1, 32); a2 += __shfl_xor(a2, 32); a3 += __shfl_xor(a3, 32);
    a4 += __shfl_xor(a4, 32); a5 += __shfl_xor(a5, 32); a6 += __shfl_xor(a6, 32); a7 += __shfl_xor(a7, 32);

    float id = 1.0f / deg[row];
    a0 *= id; a1 *= id; a2 *= id; a3 *= id; a4 *= id; a5 *= id; a6 *= id; a7 *= id;

    float ss = a0 * a0 + a1 * a1 + a2 * a2 + a3 * a3 + a4 * a4 + a5 * a5 + a6 * a6 + a7 * a7;
#pragma unroll
    for (int m = 1; m <= 8; m <<= 1) ss += __shfl_xor(ss, m);  // across 16 subs
    float nrm = fmaxf(sqrtf(ss), 1e-12f);

    if (lane < 16) {
        x_next4[(size_t)row * 16 + sub] = make_uint4(pack2bf(a0, a1), pack2bf(a2, a3),
                                                     pack2bf(a4, a5), pack2bf(a6, a7));
    }
    if (lane == 0) s_out[row] = weight / nrm;
}

// ---------------- combine 4 hops into acc (d_out) + column partial stats ----------------
// 1024 blocks x 256 threads; thread t = (row-group t>>4, sub t&15).
static __global__ __launch_bounds__(256) void combine_stats_kernel(
    const uint4* __restrict__ x1, const uint4* __restrict__ x2,
    const uint4* __restrict__ x3, const uint4* __restrict__ x4,
    const float* __restrict__ s1, const float* __restrict__ s2,
    const float* __restrict__ s3, const float* __restrict__ s4,
    float* __restrict__ out, double* __restrict__ psum, double* __restrict__ psumsq) {
    __shared__ double shs[256 * 8];
    __shared__ double shq[256 * 8];
    int t = threadIdx.x;
    int sub = t & 15;
    int ro = t >> 4;
    int rbeg = blockIdx.x * CS_ROWS;
    int rend = rbeg + CS_ROWS; if (rend > NN) rend = NN;

    double ls[8], lq[8];
#pragma unroll
    for (int j = 0; j < 8; ++j) { ls[j] = 0.0; lq[j] = 0.0; }

    float4* out4 = (float4*)out;
    for (int r = rbeg + ro; r < rend; r += 16) {
        float w1 = s1[r], w2 = s2[r], w3 = s3[r], w4 = s4[r];
        size_t xi = (size_t)r * 16 + sub;
        uint4 q1 = x1[xi], q2 = x2[xi], q3 = x3[xi], q4 = x4[xi];
        float v[8];
        v[0] = w1 * blo(q1.x) + w2 * blo(q2.x) + w3 * blo(q3.x) + w4 * blo(q4.x);
        v[1] = w1 * bhi(q1.x) + w2 * bhi(q2.x) + w3 * bhi(q3.x) + w4 * bhi(q4.x);
        v[2] = w1 * blo(q1.y) + w2 * blo(q2.y) + w3 * blo(q3.y) + w4 * blo(q4.y);
        v[3] = w1 * bhi(q1.y) + w2 * bhi(q2.y) + w3 * bhi(q3.y) + w4 * bhi(q4.y);
        v[4] = w1 * blo(q1.z) + w2 * blo(q2.z) + w3 * blo(q3.z) + w4 * blo(q4.z);
        v[5] = w1 * bhi(q1.z) + w2 * bhi(q2.z) + w3 * bhi(q3.z) + w4 * bhi(q4.z);
        v[6] = w1 * blo(q1.w) + w2 * blo(q2.w) + w3 * blo(q3.w) + w4 * blo(q4.w);
        v[7] = w1 * bhi(q1.w) + w2 * bhi(q2.w) + w3 * bhi(q3.w) + w4 * bhi(q4.w);
        out4[(size_t)r * 32 + sub * 2]     = make_float4(v[0], v[1], v[2], v[3]);
        out4[(size_t)r * 32 + sub * 2 + 1] = make_float4(v[4], v[5], v[6], v[7]);
#pragma unroll
        for (int j = 0; j < 8; ++j) { ls[j] += (double)v[j]; lq[j] += (double)v[j] * (double)v[j]; }
    }
#pragma unroll
    for (int j = 0; j < 8; ++j) { shs[t * 8 + j] = ls[j]; shq[t * 8 + j] = lq[j]; }
    __syncthreads();
    if (t < DD) {  // column c = t; sub = c>>3, j = c&7; fold 16 row-groups
        int cs = t >> 3, cj = t & 7;
        double s = 0.0, q = 0.0;
        for (int g = 0; g < 16; ++g) {
            int src = (g * 16 + cs) * 8 + cj;
            s += shs[src];
            q += shq[src];
        }
        psum[(size_t)blockIdx.x * DD + t] = s;
        psumsq[(size_t)blockIdx.x * DD + t] = q;
    }
}

// ---------------- fold partials per column, compute mean/invstd ----------------
static __global__ __launch_bounds__(256) void colstats_fold_kernel(
    const double* __restrict__ psum, const double* __restrict__ psumsq,
    float* __restrict__ mean, float* __restrict__ invstd) {
    __shared__ double ss[256], qq[256];
    int c = blockIdx.x;   // 0..127
    int t = threadIdx.x;
    double s = 0.0, q = 0.0;
    for (int b = t; b < CS1_NBLK; b += 256) {
        s += psum[(size_t)b * DD + c];
        q += psumsq[(size_t)b * DD + c];
    }
    ss[t] = s; qq[t] = q;
    __syncthreads();
    for (int off = 128; off > 0; off >>= 1) {
        if (t < off) { ss[t] += ss[t + off]; qq[t] += qq[t + off]; }
        __syncthreads();
    }
    if (t == 0) {
        double m = ss[0] / (double)NN;
        double var = (qq[0] - (double)NN * m * m) / (double)(NN - 1);
        if (var < 0.0) var = 0.0;
        double sd = sqrt(var);
        if (sd == 0.0) sd = 1.0;
        mean[c] = (float)m;
        invstd[c] = (float)(1.0 / sd);
    }
}

static __global__ void normalize_kernel(float* __restrict__ out, const float* __restrict__ mean,
                                        const float* __restrict__ invstd, int total) {
    int i = blockIdx.x * blockDim.x + threadIdx.x;
    if (i < total) {
        int c = i & 127;
        out[i] = (out[i] - mean[c]) * invstd[c];
    }
}

extern "C" void kernel_launch(void* const* d_in, const int* in_sizes, int n_in,
                              void* d_out, int out_size, void* d_ws, size_t ws_size,
                              hipStream_t stream) {
    const int* erow = (const int*)d_in[0];
    const int* ecol = (const int*)d_in[1];
    const float* eval_ = (const float*)d_in[2];
    const float* R = (const float*)d_in[3];
    float* out = (float*)d_out;

    // workspace layout
    char* ws = (char*)d_ws;
    size_t off = 0;
    auto alloc = [&](size_t bytes) -> char* {
        char* p = ws + off;
        off += (bytes + 255) & ~(size_t)255;
        return p;
    };
    float* deg          = (float*)alloc(NN * sizeof(float));
    int* bucket_cursor  = (int*)alloc(NBKT * sizeof(int));
    int* bucket_base    = (int*)alloc(NBKT * sizeof(int));
    int* row_start      = (int*)alloc((NN + 1) * sizeof(int));
    uint2* binned       = (uint2*)alloc((size_t)NBKT * BCAP * sizeof(uint2));
    uint2* csr          = (uint2*)alloc((size_t)NE * sizeof(uint2));
    uint4* x0           = (uint4*)alloc((size_t)NN * 16 * sizeof(uint4));  // bf16 packed
    uint4* x1           = (uint4*)alloc((size_t)NN * 16 * sizeof(uint4));
    uint4* x2           = (uint4*)alloc((size_t)NN * 16 * sizeof(uint4));
    uint4* x3           = (uint4*)alloc((size_t)NN * 16 * sizeof(uint4));
    uint4* x4           = (uint4*)alloc((size_t)NN * 16 * sizeof(uint4));
    float* s1           = (float*)alloc(NN * sizeof(float));
    float* s2           = (float*)alloc(NN * sizeof(float));
    float* s3           = (float*)alloc(NN * sizeof(float));
    float* s4           = (float*)alloc(NN * sizeof(float));
    double* psum        = (double*)alloc((size_t)CS1_NBLK * DD * sizeof(double));
    double* psumsq      = (double*)alloc((size_t)CS1_NBLK * DD * sizeof(double));
    float* meanbuf      = (float*)alloc(DD * sizeof(float));
    float* invstdb      = (float*)alloc(DD * sizeof(float));

    hipMemsetAsync(bucket_cursor, 0, NBKT * sizeof(int), stream);

    const int total = NN * DD;
    const int nquads = total / 8;

    bin_kernel<<<NCHUNK, 256, 0, stream>>>(erow, ecol, eval_, bucket_cursor, binned);
    bucket_scan_kernel<<<1, 256, 0, stream>>>(bucket_cursor, bucket_base);
    sort_kernel<<<NBKT, 256, 0, stream>>>(binned, bucket_cursor, bucket_base, csr, row_start);

    deg_from_csr_kernel<<<(NN + 255) / 256, 256, 0, stream>>>(row_start, csr, deg, NN);
    init_x_kernel<<<(nquads + 255) / 256, 256, 0, stream>>>(R, deg, x0, nquads);

    spmm_fused_kernel<<<NN / 4, 256, 0, stream>>>(row_start, csr, x0, deg, x1, s1, 1.0f);
    spmm_fused_kernel<<<NN / 4, 256, 0, stream>>>(row_start, csr, x1, deg, x2, s2, 1.0f);
    spmm_fused_kernel<<<NN / 4, 256, 0, stream>>>(row_start, csr, x2, deg, x3, s3, 7.81f);
    spmm_fused_kernel<<<NN / 4, 256, 0, stream>>>(row_start, csr, x3, deg, x4, s4, 45.28f);

    combine_stats_kernel<<<CS1_NBLK, 256, 0, stream>>>(x1, x2, x3, x4, s1, s2, s3, s4,
                                                       out, psum, psumsq);
    colstats_fold_kernel<<<DD, 256, 0, stream>>>(psum, psumsq, meanbuf, invstdb);
    normalize_kernel<<<(total + 255) / 256, 256, 0, stream>>>(out, meanbuf, invstdb, total);
}

// Round 9
// 253.432 us; speedup vs baseline: 1.3719x; 1.0798x over previous
//
#include <hip/hip_runtime.h>
#include <math.h>

#define NN 50000
#define NE 800000
#define DD 128
#define NBKT 196            // coarse buckets: row >> 8
#define BCAP 5120           // per-bucket capacity (mean 4082 -> 16-sigma margin)
#define CHUNK 2048          // edges per bin_kernel block
#define NCHUNK ((NE + CHUNK - 1) / CHUNK)   // 391
#define CS1_NBLK 1024       // stats pass-1 blocks
#define CS_ROWS 49          // rows per pass-1 block (1024*49 >= 50000)

// ---------------- bf16 helpers (x stored as bf16 pairs packed in uint) ----------------
static __device__ __forceinline__ float blo(unsigned int p) { return __uint_as_float(p << 16); }
static __device__ __forceinline__ float bhi(unsigned int p) { return __uint_as_float(p & 0xffff0000u); }
static __device__ __forceinline__ unsigned int pack2bf(float a, float b) {
    unsigned int ua = __float_as_uint(a);
    unsigned int ub = __float_as_uint(b);
    ua = ua + 0x7FFFu + ((ua >> 16) & 1u);
    ub = ub + 0x7FFFu + ((ub >> 16) & 1u);
    return (ua >> 16) | (ub & 0xffff0000u);
}

// ---------------- pass 1: LDS counting-sort edges into 196 coarse buckets ----------------
// payload: uint2{ row | col<<16, val_bits }  (row, col < 65536)
static __global__ __launch_bounds__(256) void bin_kernel(
    const int* __restrict__ erow, const int* __restrict__ ecol, const float* __restrict__ eval_,
    int* __restrict__ bucket_cursor, uint2* __restrict__ binned) {
    __shared__ uint2 sorted[CHUNK];
    __shared__ unsigned short sbin[CHUNK];
    __shared__ int hist[NBKT];
    __shared__ int bstart[NBKT];
    __shared__ int bcur[NBKT];
    __shared__ int gbase[NBKT];
    __shared__ int tmp[256];

    int t = threadIdx.x;
    int cbase = blockIdx.x * CHUNK;
    int cn = NE - cbase; if (cn > CHUNK) cn = CHUNK;

    for (int i = t; i < NBKT; i += 256) hist[i] = 0;
    __syncthreads();

    unsigned int rc[8]; unsigned int vv[8]; int bb[8];
    int nloc = 0;
    for (int i = t; i < cn; i += 256) {
        int g = cbase + i;
        int r = erow[g];
        int c = ecol[g];
        float v = eval_[g];
        rc[nloc] = (unsigned)r | ((unsigned)c << 16);
        vv[nloc] = __float_as_uint(v);
        int b = r >> 8;
        bb[nloc] = b;
        atomicAdd(&hist[b], 1);
        ++nloc;
    }
    __syncthreads();

    // exclusive scan of hist -> bstart (256-thread Hillis-Steele)
    int hv = (t < NBKT) ? hist[t] : 0;
    tmp[t] = hv;
    __syncthreads();
    for (int off = 1; off < 256; off <<= 1) {
        int u = (t >= off) ? tmp[t - off] : 0;
        __syncthreads();
        tmp[t] += u;
        __syncthreads();
    }
    if (t < NBKT) {
        int ex = tmp[t] - hv;
        bstart[t] = ex;
        bcur[t] = ex;
        gbase[t] = atomicAdd(&bucket_cursor[t], hv);  // reserve contiguous run in bucket region
    }
    __syncthreads();

    // scatter into LDS (sorted by bucket)
    for (int k = 0; k < nloc; ++k) {
        int pos = atomicAdd(&bcur[bb[k]], 1);
        sorted[pos] = make_uint2(rc[k], vv[k]);
        sbin[pos] = (unsigned short)bb[k];
    }
    __syncthreads();

    // coalesced write-out: consecutive i in same bucket -> consecutive global slots
    for (int i = t; i < cn; i += 256) {
        int b = sbin[i];
        binned[(size_t)b * BCAP + gbase[b] + (i - bstart[b])] = sorted[i];
    }
}

// ---------------- exclusive scan of bucket totals ----------------
static __global__ void bucket_scan_kernel(const int* __restrict__ bucket_cursor,
                                          int* __restrict__ bucket_base) {
    __shared__ int tmp[256];
    int t = threadIdx.x;
    int v = (t < NBKT) ? bucket_cursor[t] : 0;
    tmp[t] = v;
    __syncthreads();
    for (int off = 1; off < 256; off <<= 1) {
        int u = (t >= off) ? tmp[t - off] : 0;
        __syncthreads();
        tmp[t] += u;
        __syncthreads();
    }
    if (t < NBKT) bucket_base[t] = tmp[t] - v;
}

// ---------------- pass 2: per-bucket sort by row -> final CSR + row_start + deg ----------
static __global__ __launch_bounds__(256) void sort_kernel(
    const uint2* __restrict__ binned, const int* __restrict__ bucket_cursor,
    const int* __restrict__ bucket_base, uint2* __restrict__ csr, int* __restrict__ row_start,
    float* __restrict__ deg) {
    __shared__ uint2 buf[BCAP];
    __shared__ int hist[256];
    __shared__ int rcur[256];
    __shared__ float fdeg[256];
    int b = blockIdx.x;
    int t = threadIdx.x;
    int cnt = bucket_cursor[b];
    int gb = bucket_base[b];
    int lo = b << 8;

    hist[t] = 0;
    fdeg[t] = 0.0f;
    __syncthreads();
    for (int i = t; i < cnt; i += 256) {
        uint2 e = binned[(size_t)b * BCAP + i];
        buf[i] = e;
        int rr = (int)(e.x & 0xFFFFu) - lo;
        atomicAdd(&hist[rr], 1);
        atomicAdd(&fdeg[rr], __uint_as_float(e.y));
    }
    __syncthreads();
    int hv = hist[t];
    rcur[t] = hv;  // inclusive-scan temp
    __syncthreads();
    for (int off = 1; off < 256; off <<= 1) {
        int u = (t >= off) ? rcur[t - off] : 0;
        __syncthreads();
        rcur[t] += u;
        __syncthreads();
    }
    int excl = rcur[t] - hv;
    int r = lo + t;
    if (r < NN) {
        row_start[r] = gb + excl;
        float d = fdeg[t];
        deg[r] = (d == 0.0f) ? 1.0f : d;
    }
    if (b == NBKT - 1 && t == 255) row_start[NN] = gb + cnt;
    rcur[t] = excl;
    __syncthreads();
    for (int i = t; i < cnt; i += 256) {
        uint2 e = buf[i];
        int rr = (int)(e.x & 0xFFFFu) - lo;
        int pos = atomicAdd(&rcur[rr], 1);
        csr[(size_t)gb + pos] = make_uint2(e.x >> 16, e.y);
    }
}

// x0 = R * deg^(-0.5), stored bf16-packed as uint4 (8 cols per lane-slot)
static __global__ void init_x_kernel(const float* __restrict__ R, const float* __restrict__ deg,
                                     uint4* __restrict__ xq, int nquads) {
    int i = blockIdx.x * blockDim.x + threadIdx.x;
    if (i < nquads) {
        float d = deg[i >> 4];  // 16 uint4 per row
        float sc = rsqrtf(d);
        const float4* R4 = (const float4*)R;
        float4 f0 = R4[i * 2];
        float4 f1 = R4[i * 2 + 1];
        xq[i] = make_uint4(pack2bf(f0.x * sc, f0.y * sc), pack2bf(f0.z * sc, f0.w * sc),
                           pack2bf(f1.x * sc, f1.y * sc), pack2bf(f1.z * sc, f1.w * sc));
    }
}

// ---------------- fused SpMM + inv_deg + row-norm scalar ----------------
// 256 threads = 4 waves; each wave handles 4 rows, one per 16-lane quarter.
// The quarter's 16 lanes each own 8 cols (uint4 of bf16) -> after the gather
// loop the quarter holds the COMPLETE output row: no cross-quarter reduction.
// x_next store is a fully coalesced 1KB/wave dwordx4 store.
static __global__ __launch_bounds__(256) void spmm_fused_kernel(
    const int* __restrict__ row_start, const uint2* __restrict__ csr,
    const uint4* __restrict__ x4, const float* __restrict__ deg,
    uint4* __restrict__ x_next4, float* __restrict__ s_out, float weight) {
    int wave = threadIdx.x >> 6;
    int lane = threadIdx.x & 63;
    int quarter = lane >> 4;  // 0..3 : which row of the wave's 4
    int sub = lane & 15;      // col group: cols [8*sub, 8*sub+7]
    int row = blockIdx.x * 16 + wave * 4 + quarter;
    int s = row_start[row];
    int e = row_start[row + 1];

    float a0 = 0.f, a1 = 0.f, a2 = 0.f, a3 = 0.f, a4 = 0.f, a5 = 0.f, a6 = 0.f, a7 = 0.f;
    for (int base = s; base < e; base += 16) {
        int j = base + sub;
        int cl = 0;
        float vl = 0.0f;
        if (j < e) { uint2 t2 = csr[j]; cl = (int)t2.x; vl = __uint_as_float(t2.y); }
        int cnt = e - base; if (cnt > 16) cnt = 16;
        for (int k = 0; k < cnt; k += 4) {  // 4 independent gathers in flight per lane
            int l0 = quarter * 16 + k;
            int c0 = __shfl(cl, l0);
            int c1 = __shfl(cl, l0 + 1);
            int c2 = __shfl(cl, l0 + 2);
            int c3 = __shfl(cl, l0 + 3);
            float v0 = __shfl(vl, l0);
            float v1 = __shfl(vl, l0 + 1);
            float v2 = __shfl(vl, l0 + 2);
            float v3 = __shfl(vl, l0 + 3);  // entries past cnt have vl=0 -> contribute 0
            uint4 p0 = x4[(size_t)c0 * 16 + sub];
            uint4 p1 = x4[(size_t)c1 * 16 + sub];
            uint4 p2 = x4[(size_t)c2 * 16 + sub];
            uint4 p3 = x4[(size_t)c3 * 16 + sub];
            a0 += v0 * blo(p0.x); a1 += v0 * bhi(p0.x); a2 += v0 * blo(p0.y); a3 += v0 * bhi(p0.y);
            a4 += v0 * blo(p0.z); a5 += v0 * bhi(p0.z); a6 += v0 * blo(p0.w); a7 += v0 * bhi(p0.w);
            a0 += v1 * blo(p1.x); a1 += v1 * bhi(p1.x); a2 += v1 * blo(p1.y); a3 += v1 * bhi(p1.y);
            a4 += v1 * blo(p1.z); a5 += v1 * bhi(p1.z); a6 += v1 * blo(p1.w); a7 += v1 * bhi(p1.w);
            a0 += v2 * blo(p2.x); a1 += v2 * bhi(p2.x); a2 += v2 * blo(p2.y); a3 += v2 * bhi(p2.y);
            a4 += v2 * blo(p2.z); a5 += v2 * bhi(p2.z); a6 += v2 * blo(p2.w); a7 += v2 * bhi(p2.w);
            a0 += v3 * blo(p3.x); a1 += v3 * bhi(p3.x); a2 += v3 * blo(p3.y); a3 += v3 * bhi(p3.y);
            a4 += v3 * blo(p3.z); a5 += v3 * bhi(p3.z); a6 += v3 * blo(p3.w); a7 += v3 * bhi(p3.w);
        }
    }

    float id = 1.0f / deg[row];
    a0 *= id; a1 *= id; a2 *= id; a3 *= id; a4 *= id; a5 *= id; a6 *= id; a7 *= id;

    // norm reduce across the quarter's 16 lanes only
    float ss = a0 * a0 + a1 * a1 + a2 * a2 + a3 * a3 + a4 * a4 + a5 * a5 + a6 * a6 + a7 * a7;
#pragma unroll
    for (int m = 1; m <= 8; m <<= 1) ss += __shfl_xor(ss, m);
    float nrm = fmaxf(sqrtf(ss), 1e-12f);

    x_next4[(size_t)row * 16 + sub] = make_uint4(pack2bf(a0, a1), pack2bf(a2, a3),
                                                 pack2bf(a4, a5), pack2bf(a6, a7));
    if (sub == 0) s_out[row] = weight / nrm;
}

// ---------------- column partial stats straight from the 4 bf16 hops ----------------
// acc[r] = sum_i s_i[r] * x_i[r]  (linear) -> stats without materializing acc.
static __global__ __launch_bounds__(256) void stats_kernel(
    const uint4* __restrict__ x1, const uint4* __restrict__ x2,
    const uint4* __restrict__ x3, const uint4* __restrict__ x4,
    const float* __restrict__ s1, const float* __restrict__ s2,
    const float* __restrict__ s3, const float* __restrict__ s4,
    double* __restrict__ psum, double* __restrict__ psumsq) {
    __shared__ double shs[256 * 8];
    __shared__ double shq[256 * 8];
    int t = threadIdx.x;
    int sub = t & 15;
    int ro = t >> 4;
    int rbeg = blockIdx.x * CS_ROWS;
    int rend = rbeg + CS_ROWS; if (rend > NN) rend = NN;

    double ls[8], lq[8];
#pragma unroll
    for (int j = 0; j < 8; ++j) { ls[j] = 0.0; lq[j] = 0.0; }

    for (int r = rbeg + ro; r < rend; r += 16) {
        float w1 = s1[r], w2 = s2[r], w3 = s3[r], w4 = s4[r];
        size_t xi = (size_t)r * 16 + sub;
        uint4 q1 = x1[xi], q2 = x2[xi], q3 = x3[xi], q4 = x4[xi];
        float v[8];
        v[0] = w1 * blo(q1.x) + w2 * blo(q2.x) + w3 * blo(q3.x) + w4 * blo(q4.x);
        v[1] = w1 * bhi(q1.x) + w2 * bhi(q2.x) + w3 * bhi(q3.x) + w4 * bhi(q4.x);
        v[2] = w1 * blo(q1.y) + w2 * blo(q2.y) + w3 * blo(q3.y) + w4 * blo(q4.y);
        v[3] = w1 * bhi(q1.y) + w2 * bhi(q2.y) + w3 * bhi(q3.y) + w4 * bhi(q4.y);
        v[4] = w1 * blo(q1.z) + w2 * blo(q2.z) + w3 * blo(q3.z) + w4 * blo(q4.z);
        v[5] = w1 * bhi(q1.z) + w2 * bhi(q2.z) + w3 * bhi(q3.z) + w4 * bhi(q4.z);
        v[6] = w1 * blo(q1.w) + w2 * blo(q2.w) + w3 * blo(q3.w) + w4 * blo(q4.w);
        v[7] = w1 * bhi(q1.w) + w2 * bhi(q2.w) + w3 * bhi(q3.w) + w4 * bhi(q4.w);
#pragma unroll
        for (int j = 0; j < 8; ++j) { ls[j] += (double)v[j]; lq[j] += (double)v[j] * (double)v[j]; }
    }
#pragma unroll
    for (int j = 0; j < 8; ++j) { shs[t * 8 + j] = ls[j]; shq[t * 8 + j] = lq[j]; }
    __syncthreads();
    if (t < DD) {  // column c = t; sub = c>>3, j = c&7; fold the 16 row-groups
        int cs = t >> 3, cj = t & 7;
        double s = 0.0, q = 0.0;
        for (int g = 0; g < 16; ++g) {
            int src = (g * 16 + cs) * 8 + cj;
            s += shs[src];
            q += shq[src];
        }
        psum[(size_t)blockIdx.x * DD + t] = s;
        psumsq[(size_t)blockIdx.x * DD + t] = q;
    }
}

// ---------------- fold partials per column, compute mean/invstd ----------------
static __global__ __launch_bounds__(256) void colstats_fold_kernel(
    const double* __restrict__ psum, const double* __restrict__ psumsq,
    float* __restrict__ mean, float* __restrict__ invstd) {
    __shared__ double ss[256], qq[256];
    int c = blockIdx.x;   // 0..127
    int t = threadIdx.x;
    double s = 0.0, q = 0.0;
    for (int b = t; b < CS1_NBLK; b += 256) {
        s += psum[(size_t)b * DD + c];
        q += psumsq[(size_t)b * DD + c];
    }
    ss[t] = s; qq[t] = q;
    __syncthreads();
    for (int off = 128; off > 0; off >>= 1) {
        if (t < off) { ss[t] += ss[t + off]; qq[t] += qq[t + off]; }
        __syncthreads();
    }
    if (t == 0) {
        double m = ss[0] / (double)NN;
        double var = (qq[0] - (double)NN * m * m) / (double)(NN - 1);
        if (var < 0.0) var = 0.0;
        double sd = sqrt(var);
        if (sd == 0.0) sd = 1.0;
        mean[c] = (float)m;
        invstd[c] = (float)(1.0 / sd);
    }
}

// ---------------- final: reconstruct acc from hops, standardize, write out ----------------
static __global__ __launch_bounds__(256) void final_kernel(
    const uint4* __restrict__ x1, const uint4* __restrict__ x2,
    const uint4* __restrict__ x3, const uint4* __restrict__ x4,
    const float* __restrict__ s1, const float* __restrict__ s2,
    const float* __restrict__ s3, const float* __restrict__ s4,
    const float* __restrict__ mean, const float* __restrict__ invstd,
    float* __restrict__ out) {
    int i = blockIdx.x * blockDim.x + threadIdx.x;  // over NN*16
    int r = i >> 4;
    int sub = i & 15;
    float w1 = s1[r], w2 = s2[r], w3 = s3[r], w4 = s4[r];
    uint4 q1 = x1[i], q2 = x2[i], q3 = x3[i], q4 = x4[i];
    float v[8];
    v[0] = w1 * blo(q1.x) + w2 * blo(q2.x) + w3 * blo(q3.x) + w4 * blo(q4.x);
    v[1] = w1 * bhi(q1.x) + w2 * bhi(q2.x) + w3 * bhi(q3.x) + w4 * bhi(q4.x);
    v[2] = w1 * blo(q1.y) + w2 * blo(q2.y) + w3 * blo(q3.y) + w4 * blo(q4.y);
    v[3] = w1 * bhi(q1.y) + w2 * bhi(q2.y) + w3 * bhi(q3.y) + w4 * bhi(q4.y);
    v[4] = w1 * blo(q1.z) + w2 * blo(q2.z) + w3 * blo(q3.z) + w4 * blo(q4.z);
    v[5] = w1 * bhi(q1.z) + w2 * bhi(q2.z) + w3 * bhi(q3.z) + w4 * bhi(q4.z);
    v[6] = w1 * blo(q1.w) + w2 * blo(q2.w) + w3 * blo(q3.w) + w4 * blo(q4.w);
    v[7] = w1 * bhi(q1.w) + w2 * bhi(q2.w) + w3 * bhi(q3.w) + w4 * bhi(q4.w);
    const float4* m4 = (const float4*)mean;
    const float4* is4 = (const float4*)invstd;
    float4 m0 = m4[sub * 2], m1 = m4[sub * 2 + 1];
    float4 i0 = is4[sub * 2], i1 = is4[sub * 2 + 1];
    float4* out4 = (float4*)out;
    out4[(size_t)i * 2]     = make_float4((v[0] - m0.x) * i0.x, (v[1] - m0.y) * i0.y,
                                          (v[2] - m0.z) * i0.z, (v[3] - m0.w) * i0.w);
    out4[(size_t)i * 2 + 1] = make_float4((v[4] - m1.x) * i1.x, (v[5] - m1.y) * i1.y,
                                          (v[6] - m1.z) * i1.z, (v[7] - m1.w) * i1.w);
}

extern "C" void kernel_launch(void* const* d_in, const int* in_sizes, int n_in,
                              void* d_out, int out_size, void* d_ws, size_t ws_size,
                              hipStream_t stream) {
    const int* erow = (const int*)d_in[0];
    const int* ecol = (const int*)d_in[1];
    const float* eval_ = (const float*)d_in[2];
    const float* R = (const float*)d_in[3];
    float* out = (float*)d_out;

    // workspace layout
    char* ws = (char*)d_ws;
    size_t off = 0;
    auto alloc = [&](size_t bytes) -> char* {
        char* p = ws + off;
        off += (bytes + 255) & ~(size_t)255;
        return p;
    };
    float* deg          = (float*)alloc(NN * sizeof(float));
    int* bucket_cursor  = (int*)alloc(NBKT * sizeof(int));
    int* bucket_base    = (int*)alloc(NBKT * sizeof(int));
    int* row_start      = (int*)alloc((NN + 1) * sizeof(int));
    uint2* binned       = (uint2*)alloc((size_t)NBKT * BCAP * sizeof(uint2));
    uint2* csr          = (uint2*)alloc((size_t)NE * sizeof(uint2));
    uint4* x0           = (uint4*)alloc((size_t)NN * 16 * sizeof(uint4));  // bf16 packed
    uint4* x1           = (uint4*)alloc((size_t)NN * 16 * sizeof(uint4));
    uint4* x2           = (uint4*)alloc((size_t)NN * 16 * sizeof(uint4));
    uint4* x3           = (uint4*)alloc((size_t)NN * 16 * sizeof(uint4));
    uint4* x4           = (uint4*)alloc((size_t)NN * 16 * sizeof(uint4));
    float* s1           = (float*)alloc(NN * sizeof(float));
    float* s2           = (float*)alloc(NN * sizeof(float));
    float* s3           = (float*)alloc(NN * sizeof(float));
    float* s4           = (float*)alloc(NN * sizeof(float));
    double* psum        = (double*)alloc((size_t)CS1_NBLK * DD * sizeof(double));
    double* psumsq      = (double*)alloc((size_t)CS1_NBLK * DD * sizeof(double));
    float* meanbuf      = (float*)alloc(DD * sizeof(float));
    float* invstdb      = (float*)alloc(DD * sizeof(float));

    hipMemsetAsync(bucket_cursor, 0, NBKT * sizeof(int), stream);

    const int total = NN * DD;
    const int nquads = total / 8;

    bin_kernel<<<NCHUNK, 256, 0, stream>>>(erow, ecol, eval_, bucket_cursor, binned);
    bucket_scan_kernel<<<1, 256, 0, stream>>>(bucket_cursor, bucket_base);
    sort_kernel<<<NBKT, 256, 0, stream>>>(binned, bucket_cursor, bucket_base, csr, row_start, deg);

    init_x_kernel<<<(nquads + 255) / 256, 256, 0, stream>>>(R, deg, x0, nquads);

    spmm_fused_kernel<<<NN / 16, 256, 0, stream>>>(row_start, csr, x0, deg, x1, s1, 1.0f);
    spmm_fused_kernel<<<NN / 16, 256, 0, stream>>>(row_start, csr, x1, deg, x2, s2, 1.0f);
    spmm_fused_kernel<<<NN / 16, 256, 0, stream>>>(row_start, csr, x2, deg, x3, s3, 7.81f);
    spmm_fused_kernel<<<NN / 16, 256, 0, stream>>>(row_start, csr, x3, deg, x4, s4, 45.28f);

    stats_kernel<<<CS1_NBLK, 256, 0, stream>>>(x1, x2, x3, x4, s1, s2, s3, s4, psum, psumsq);
    colstats_fold_kernel<<<DD, 256, 0, stream>>>(psum, psumsq, meanbuf, invstdb);
    final_kernel<<<NN * 16 / 256, 256, 0, stream>>>(x1, x2, x3, x4, s1, s2, s3, s4,
                                                    meanbuf, invstdb, out);
}

// Round 10
// 251.979 us; speedup vs baseline: 1.3799x; 1.0058x over previous
//
#include <hip/hip_runtime.h>
#include <math.h>

#define NN 50000
#define NE 800000
#define DD 128
#define NBKT 196            // coarse buckets: row >> 8
#define BCAP 5120           // per-bucket capacity (mean 4082 -> 16-sigma margin)
#define CHUNK 2048          // edges per bin_kernel block
#define NCHUNK ((NE + CHUNK - 1) / CHUNK)   // 391
#define SPMM_NBLK (NN / 16) // 3125

// ---------------- bf16 helpers (x stored as bf16 pairs packed in uint) ----------------
static __device__ __forceinline__ float blo(unsigned int p) { return __uint_as_float(p << 16); }
static __device__ __forceinline__ float bhi(unsigned int p) { return __uint_as_float(p & 0xffff0000u); }
static __device__ __forceinline__ unsigned int pack2bf(float a, float b) {
    unsigned int ua = __float_as_uint(a);
    unsigned int ub = __float_as_uint(b);
    ua = ua + 0x7FFFu + ((ua >> 16) & 1u);
    ub = ub + 0x7FFFu + ((ub >> 16) & 1u);
    return (ua >> 16) | (ub & 0xffff0000u);
}

// ---------------- pass 1: LDS counting-sort edges into 196 coarse buckets ----------------
// payload: uint2{ row | col<<16, val_bits }  (row, col < 65536)
static __global__ __launch_bounds__(256) void bin_kernel(
    const int* __restrict__ erow, const int* __restrict__ ecol, const float* __restrict__ eval_,
    int* __restrict__ bucket_cursor, uint2* __restrict__ binned) {
    __shared__ uint2 sorted[CHUNK];
    __shared__ unsigned short sbin[CHUNK];
    __shared__ int hist[NBKT];
    __shared__ int bstart[NBKT];
    __shared__ int bcur[NBKT];
    __shared__ int gbase[NBKT];
    __shared__ int tmp[256];

    int t = threadIdx.x;
    int cbase = blockIdx.x * CHUNK;
    int cn = NE - cbase; if (cn > CHUNK) cn = CHUNK;

    for (int i = t; i < NBKT; i += 256) hist[i] = 0;
    __syncthreads();

    unsigned int rc[8]; unsigned int vv[8]; int bb[8];
    int nloc = 0;
    for (int i = t; i < cn; i += 256) {
        int g = cbase + i;
        int r = erow[g];
        int c = ecol[g];
        float v = eval_[g];
        rc[nloc] = (unsigned)r | ((unsigned)c << 16);
        vv[nloc] = __float_as_uint(v);
        int b = r >> 8;
        bb[nloc] = b;
        atomicAdd(&hist[b], 1);
        ++nloc;
    }
    __syncthreads();

    // exclusive scan of hist -> bstart (256-thread Hillis-Steele)
    int hv = (t < NBKT) ? hist[t] : 0;
    tmp[t] = hv;
    __syncthreads();
    for (int off = 1; off < 256; off <<= 1) {
        int u = (t >= off) ? tmp[t - off] : 0;
        __syncthreads();
        tmp[t] += u;
        __syncthreads();
    }
    if (t < NBKT) {
        int ex = tmp[t] - hv;
        bstart[t] = ex;
        bcur[t] = ex;
        gbase[t] = atomicAdd(&bucket_cursor[t], hv);  // reserve contiguous run in bucket region
    }
    __syncthreads();

    // scatter into LDS (sorted by bucket)
    for (int k = 0; k < nloc; ++k) {
        int pos = atomicAdd(&bcur[bb[k]], 1);
        sorted[pos] = make_uint2(rc[k], vv[k]);
        sbin[pos] = (unsigned short)bb[k];
    }
    __syncthreads();

    // coalesced write-out: consecutive i in same bucket -> consecutive global slots
    for (int i = t; i < cn; i += 256) {
        int b = sbin[i];
        binned[(size_t)b * BCAP + gbase[b] + (i - bstart[b])] = sorted[i];
    }
}

// ---------------- pass 2: per-bucket sort by row -> CSR + row_start + deg + x0 ----------
// Fuses: bucket prefix scan (each block scans the 196 counters itself),
// degree computation, and x0 = R * deg^(-1/2) bf16 init for the block's rows.
static __global__ __launch_bounds__(256) void sort_kernel(
    const uint2* __restrict__ binned, const int* __restrict__ bucket_cursor,
    uint2* __restrict__ csr, int* __restrict__ row_start, float* __restrict__ deg,
    const float* __restrict__ R, uint4* __restrict__ x0) {
    __shared__ uint2 buf[BCAP];
    __shared__ int hist[256];
    __shared__ int rcur[256];
    __shared__ float fdeg[256];
    __shared__ int pscan[256];
    int b = blockIdx.x;
    int t = threadIdx.x;
    int lo = b << 8;

    // inclusive scan over all bucket counts -> per-block base + count
    int pv = (t < NBKT) ? bucket_cursor[t] : 0;
    pscan[t] = pv;
    hist[t] = 0;
    fdeg[t] = 0.0f;
    __syncthreads();
    for (int off = 1; off < 256; off <<= 1) {
        int u = (t >= off) ? pscan[t - off] : 0;
        __syncthreads();
        pscan[t] += u;
        __syncthreads();
    }
    int gb = (b == 0) ? 0 : pscan[b - 1];
    int cnt = pscan[b] - gb;

    for (int i = t; i < cnt; i += 256) {
        uint2 e = binned[(size_t)b * BCAP + i];
        buf[i] = e;
        int rr = (int)(e.x & 0xFFFFu) - lo;
        atomicAdd(&hist[rr], 1);
        atomicAdd(&fdeg[rr], __uint_as_float(e.y));
    }
    __syncthreads();
    int hv = hist[t];
    rcur[t] = hv;  // inclusive-scan temp
    __syncthreads();
    for (int off = 1; off < 256; off <<= 1) {
        int u = (t >= off) ? rcur[t - off] : 0;
        __syncthreads();
        rcur[t] += u;
        __syncthreads();
    }
    int excl = rcur[t] - hv;
    int r = lo + t;
    if (r < NN) {
        row_start[r] = gb + excl;
        float d = fdeg[t];
        deg[r] = (d == 0.0f) ? 1.0f : d;
    }
    if (b == NBKT - 1 && t == 255) row_start[NN] = gb + cnt;
    rcur[t] = excl;
    __syncthreads();
    for (int i = t; i < cnt; i += 256) {
        uint2 e = buf[i];
        int rr = (int)(e.x & 0xFFFFu) - lo;
        int pos = atomicAdd(&rcur[rr], 1);
        csr[(size_t)gb + pos] = make_uint2(e.x >> 16, e.y);
    }

    // x0 init for this block's rows (fdeg already in LDS)
    int nrows = NN - lo; if (nrows > 256) nrows = 256;
    const float4* __restrict__ R4 = (const float4*)R;
    for (int idx = t; idx < nrows * 16; idx += 256) {
        int rr = idx >> 4;
        int sub = idx & 15;
        float d = fdeg[rr];
        d = (d == 0.0f) ? 1.0f : d;
        float sc = rsqrtf(d);
        size_t g = (size_t)(lo + rr) * 16 + sub;
        float4 f0 = R4[g * 2];
        float4 f1 = R4[g * 2 + 1];
        x0[g] = make_uint4(pack2bf(f0.x * sc, f0.y * sc), pack2bf(f0.z * sc, f0.w * sc),
                           pack2bf(f1.x * sc, f1.y * sc), pack2bf(f1.z * sc, f1.w * sc));
    }
}

// ---------------- fused SpMM + inv_deg + row-norm scalar (hops 1-3) ----------------
// 256 threads = 4 waves; each wave handles 4 rows, one per 16-lane quarter.
static __global__ __launch_bounds__(256) void spmm_fused_kernel(
    const int* __restrict__ row_start, const uint2* __restrict__ csr,
    const uint4* __restrict__ x4, const float* __restrict__ deg,
    uint4* __restrict__ x_next4, float* __restrict__ s_out, float weight) {
    int wave = threadIdx.x >> 6;
    int lane = threadIdx.x & 63;
    int quarter = lane >> 4;  // 0..3 : which row of the wave's 4
    int sub = lane & 15;      // col group: cols [8*sub, 8*sub+7]
    int row = blockIdx.x * 16 + wave * 4 + quarter;
    int s = row_start[row];
    int e = row_start[row + 1];

    float a0 = 0.f, a1 = 0.f, a2 = 0.f, a3 = 0.f, a4 = 0.f, a5 = 0.f, a6 = 0.f, a7 = 0.f;
    for (int base = s; base < e; base += 16) {
        int j = base + sub;
        int cl = 0;
        float vl = 0.0f;
        if (j < e) { uint2 t2 = csr[j]; cl = (int)t2.x; vl = __uint_as_float(t2.y); }
        int cnt = e - base; if (cnt > 16) cnt = 16;
        for (int k = 0; k < cnt; k += 4) {
            int l0 = quarter * 16 + k;
            int c0 = __shfl(cl, l0);
            int c1 = __shfl(cl, l0 + 1);
            int c2 = __shfl(cl, l0 + 2);
            int c3 = __shfl(cl, l0 + 3);
            float v0 = __shfl(vl, l0);
            float v1 = __shfl(vl, l0 + 1);
            float v2 = __shfl(vl, l0 + 2);
            float v3 = __shfl(vl, l0 + 3);  // entries past cnt have vl=0 -> contribute 0
            uint4 p0 = x4[(size_t)c0 * 16 + sub];
            uint4 p1 = x4[(size_t)c1 * 16 + sub];
            uint4 p2 = x4[(size_t)c2 * 16 + sub];
            uint4 p3 = x4[(size_t)c3 * 16 + sub];
            a0 += v0 * blo(p0.x); a1 += v0 * bhi(p0.x); a2 += v0 * blo(p0.y); a3 += v0 * bhi(p0.y);
            a4 += v0 * blo(p0.z); a5 += v0 * bhi(p0.z); a6 += v0 * blo(p0.w); a7 += v0 * bhi(p0.w);
            a0 += v1 * blo(p1.x); a1 += v1 * bhi(p1.x); a2 += v1 * blo(p1.y); a3 += v1 * bhi(p1.y);
            a4 += v1 * blo(p1.z); a5 += v1 * bhi(p1.z); a6 += v1 * blo(p1.w); a7 += v1 * bhi(p1.w);
            a0 += v2 * blo(p2.x); a1 += v2 * bhi(p2.x); a2 += v2 * blo(p2.y); a3 += v2 * bhi(p2.y);
            a4 += v2 * blo(p2.z); a5 += v2 * bhi(p2.z); a6 += v2 * blo(p2.w); a7 += v2 * bhi(p2.w);
            a0 += v3 * blo(p3.x); a1 += v3 * bhi(p3.x); a2 += v3 * blo(p3.y); a3 += v3 * bhi(p3.y);
            a4 += v3 * blo(p3.z); a5 += v3 * bhi(p3.z); a6 += v3 * blo(p3.w); a7 += v3 * bhi(p3.w);
        }
    }

    float id = 1.0f / deg[row];
    a0 *= id; a1 *= id; a2 *= id; a3 *= id; a4 *= id; a5 *= id; a6 *= id; a7 *= id;

    float ss = a0 * a0 + a1 * a1 + a2 * a2 + a3 * a3 + a4 * a4 + a5 * a5 + a6 * a6 + a7 * a7;
#pragma unroll
    for (int m = 1; m <= 8; m <<= 1) ss += __shfl_xor(ss, m);
    float nrm = fmaxf(sqrtf(ss), 1e-12f);

    x_next4[(size_t)row * 16 + sub] = make_uint4(pack2bf(a0, a1), pack2bf(a2, a3),
                                                 pack2bf(a4, a5), pack2bf(a6, a7));
    if (sub == 0) s_out[row] = weight / nrm;
}

// ---------------- hop 4: SpMM + combine acc(out) + per-block column stats ----------------
// Same gather; epilogue reads x1..x3 + s1..s3 for its row, writes acc (f32) to out,
// and reduces per-block column partial sum/sumsq into psum/psumsq (f32, 16 rows/block).
static __global__ __launch_bounds__(256) void spmm_last_kernel(
    const int* __restrict__ row_start, const uint2* __restrict__ csr,
    const uint4* __restrict__ xin, const float* __restrict__ deg,
    const uint4* __restrict__ x1, const uint4* __restrict__ x2, const uint4* __restrict__ x3,
    const float* __restrict__ s1, const float* __restrict__ s2, const float* __restrict__ s3,
    float* __restrict__ out, float* __restrict__ psum, float* __restrict__ psumsq, float weight) {
    __shared__ float shs[256 * 8];
    __shared__ float shq[256 * 8];
    int wave = threadIdx.x >> 6;
    int lane = threadIdx.x & 63;
    int quarter = lane >> 4;
    int sub = lane & 15;
    int row = blockIdx.x * 16 + wave * 4 + quarter;
    int s = row_start[row];
    int e = row_start[row + 1];

    float a0 = 0.f, a1 = 0.f, a2 = 0.f, a3 = 0.f, a4 = 0.f, a5 = 0.f, a6 = 0.f, a7 = 0.f;
    for (int base = s; base < e; base += 16) {
        int j = base + sub;
        int cl = 0;
        float vl = 0.0f;
        if (j < e) { uint2 t2 = csr[j]; cl = (int)t2.x; vl = __uint_as_float(t2.y); }
        int cnt = e - base; if (cnt > 16) cnt = 16;
        for (int k = 0; k < cnt; k += 4) {
            int l0 = quarter * 16 + k;
            int c0 = __shfl(cl, l0);
            int c1 = __shfl(cl, l0 + 1);
            int c2 = __shfl(cl, l0 + 2);
            int c3 = __shfl(cl, l0 + 3);
            float v0 = __shfl(vl, l0);
            float v1 = __shfl(vl, l0 + 1);
            float v2 = __shfl(vl, l0 + 2);
            float v3 = __shfl(vl, l0 + 3);
            uint4 p0 = xin[(size_t)c0 * 16 + sub];
            uint4 p1 = xin[(size_t)c1 * 16 + sub];
            uint4 p2 = xin[(size_t)c2 * 16 + sub];
            uint4 p3 = xin[(size_t)c3 * 16 + sub];
            a0 += v0 * blo(p0.x); a1 += v0 * bhi(p0.x); a2 += v0 * blo(p0.y); a3 += v0 * bhi(p0.y);
            a4 += v0 * blo(p0.z); a5 += v0 * bhi(p0.z); a6 += v0 * blo(p0.w); a7 += v0 * bhi(p0.w);
            a0 += v1 * blo(p1.x); a1 += v1 * bhi(p1.x); a2 += v1 * blo(p1.y); a3 += v1 * bhi(p1.y);
            a4 += v1 * blo(p1.z); a5 += v1 * bhi(p1.z); a6 += v1 * blo(p1.w); a7 += v1 * bhi(p1.w);
            a0 += v2 * blo(p2.x); a1 += v2 * bhi(p2.x); a2 += v2 * blo(p2.y); a3 += v2 * bhi(p2.y);
            a4 += v2 * blo(p2.z); a5 += v2 * bhi(p2.z); a6 += v2 * blo(p2.w); a7 += v2 * bhi(p2.w);
            a0 += v3 * blo(p3.x); a1 += v3 * bhi(p3.x); a2 += v3 * blo(p3.y); a3 += v3 * bhi(p3.y);
            a4 += v3 * blo(p3.z); a5 += v3 * bhi(p3.z); a6 += v3 * blo(p3.w); a7 += v3 * bhi(p3.w);
        }
    }

    float id = 1.0f / deg[row];
    a0 *= id; a1 *= id; a2 *= id; a3 *= id; a4 *= id; a5 *= id; a6 *= id; a7 *= id;

    float ss = a0 * a0 + a1 * a1 + a2 * a2 + a3 * a3 + a4 * a4 + a5 * a5 + a6 * a6 + a7 * a7;
#pragma unroll
    for (int m = 1; m <= 8; m <<= 1) ss += __shfl_xor(ss, m);
    float nrm = fmaxf(sqrtf(ss), 1e-12f);
    float w4 = weight / nrm;

    // combine: acc = s1*x1 + s2*x2 + s3*x3 + w4 * (f32 hop-4 row)
    size_t xi = (size_t)row * 16 + sub;
    float w1 = s1[row], w2 = s2[row], w3 = s3[row];
    uint4 q1 = x1[xi], q2 = x2[xi], q3 = x3[xi];
    float v[8];
    v[0] = w1 * blo(q1.x) + w2 * blo(q2.x) + w3 * blo(q3.x) + w4 * a0;
    v[1] = w1 * bhi(q1.x) + w2 * bhi(q2.x) + w3 * bhi(q3.x) + w4 * a1;
    v[2] = w1 * blo(q1.y) + w2 * blo(q2.y) + w3 * blo(q3.y) + w4 * a2;
    v[3] = w1 * bhi(q1.y) + w2 * bhi(q2.y) + w3 * bhi(q3.y) + w4 * a3;
    v[4] = w1 * blo(q1.z) + w2 * blo(q2.z) + w3 * blo(q3.z) + w4 * a4;
    v[5] = w1 * bhi(q1.z) + w2 * bhi(q2.z) + w3 * bhi(q3.z) + w4 * a5;
    v[6] = w1 * blo(q1.w) + w2 * blo(q2.w) + w3 * blo(q3.w) + w4 * a6;
    v[7] = w1 * bhi(q1.w) + w2 * bhi(q2.w) + w3 * bhi(q3.w) + w4 * a7;

    float4* out4 = (float4*)out;
    out4[(size_t)row * 32 + sub * 2]     = make_float4(v[0], v[1], v[2], v[3]);
    out4[(size_t)row * 32 + sub * 2 + 1] = make_float4(v[4], v[5], v[6], v[7]);

    int t = threadIdx.x;
#pragma unroll
    for (int j = 0; j < 8; ++j) {
        shs[t * 8 + j] = v[j];
        shq[t * 8 + j] = v[j] * v[j];
    }
    __syncthreads();
    if (t < DD) {  // column c = t; fold the 16 rows of this block
        int cs = t >> 3, cj = t & 7;
        float sacc = 0.0f, qacc = 0.0f;
        for (int g = 0; g < 16; ++g) {
            int src = (g * 16 + cs) * 8 + cj;
            sacc += shs[src];
            qacc += shq[src];
        }
        psum[(size_t)blockIdx.x * DD + t] = sacc;
        psumsq[(size_t)blockIdx.x * DD + t] = qacc;
    }
}

// ---------------- fold partials per column, compute mean/invstd ----------------
static __global__ __launch_bounds__(256) void fold_kernel(
    const float* __restrict__ psum, const float* __restrict__ psumsq,
    float* __restrict__ mean, float* __restrict__ invstd) {
    __shared__ double ss[256], qq[256];
    int c = blockIdx.x;   // 0..127
    int t = threadIdx.x;
    double s = 0.0, q = 0.0;
    for (int b = t; b < SPMM_NBLK; b += 256) {
        s += (double)psum[(size_t)b * DD + c];
        q += (double)psumsq[(size_t)b * DD + c];
    }
    ss[t] = s; qq[t] = q;
    __syncthreads();
    for (int off = 128; off > 0; off >>= 1) {
        if (t < off) { ss[t] += ss[t + off]; qq[t] += qq[t + off]; }
        __syncthreads();
    }
    if (t == 0) {
        double m = ss[0] / (double)NN;
        double var = (qq[0] - (double)NN * m * m) / (double)(NN - 1);
        if (var < 0.0) var = 0.0;
        double sd = sqrt(var);
        if (sd == 0.0) sd = 1.0;
        mean[c] = (float)m;
        invstd[c] = (float)(1.0 / sd);
    }
}

// ---------------- standardize in place (float4 vectorized) ----------------
static __global__ __launch_bounds__(256) void normalize_kernel(
    float* __restrict__ out, const float* __restrict__ mean, const float* __restrict__ invstd) {
    int i = blockIdx.x * blockDim.x + threadIdx.x;  // over NN*32 float4s
    int c4 = i & 31;
    float4 m = ((const float4*)mean)[c4];
    float4 is = ((const float4*)invstd)[c4];
    float4* out4 = (float4*)out;
    float4 v = out4[i];
    v.x = (v.x - m.x) * is.x;
    v.y = (v.y - m.y) * is.y;
    v.z = (v.z - m.z) * is.z;
    v.w = (v.w - m.w) * is.w;
    out4[i] = v;
}

extern "C" void kernel_launch(void* const* d_in, const int* in_sizes, int n_in,
                              void* d_out, int out_size, void* d_ws, size_t ws_size,
                              hipStream_t stream) {
    const int* erow = (const int*)d_in[0];
    const int* ecol = (const int*)d_in[1];
    const float* eval_ = (const float*)d_in[2];
    const float* R = (const float*)d_in[3];
    float* out = (float*)d_out;

    // workspace layout
    char* ws = (char*)d_ws;
    size_t off = 0;
    auto alloc = [&](size_t bytes) -> char* {
        char* p = ws + off;
        off += (bytes + 255) & ~(size_t)255;
        return p;
    };
    float* deg          = (float*)alloc(NN * sizeof(float));
    int* bucket_cursor  = (int*)alloc(NBKT * sizeof(int));
    int* row_start      = (int*)alloc((NN + 1) * sizeof(int));
    uint2* binned       = (uint2*)alloc((size_t)NBKT * BCAP * sizeof(uint2));
    uint2* csr          = (uint2*)alloc((size_t)NE * sizeof(uint2));
    uint4* x0           = (uint4*)alloc((size_t)NN * 16 * sizeof(uint4));  // bf16 packed
    uint4* x1           = (uint4*)alloc((size_t)NN * 16 * sizeof(uint4));
    uint4* x2           = (uint4*)alloc((size_t)NN * 16 * sizeof(uint4));
    uint4* x3           = (uint4*)alloc((size_t)NN * 16 * sizeof(uint4));
    float* s1           = (float*)alloc(NN * sizeof(float));
    float* s2           = (float*)alloc(NN * sizeof(float));
    float* s3           = (float*)alloc(NN * sizeof(float));
    float* psum         = (float*)alloc((size_t)SPMM_NBLK * DD * sizeof(float));
    float* psumsq       = (float*)alloc((size_t)SPMM_NBLK * DD * sizeof(float));
    float* meanbuf      = (float*)alloc(DD * sizeof(float));
    float* invstdb      = (float*)alloc(DD * sizeof(float));

    hipMemsetAsync(bucket_cursor, 0, NBKT * sizeof(int), stream);

    bin_kernel<<<NCHUNK, 256, 0, stream>>>(erow, ecol, eval_, bucket_cursor, binned);
    sort_kernel<<<NBKT, 256, 0, stream>>>(binned, bucket_cursor, csr, row_start, deg, R, x0);

    spmm_fused_kernel<<<SPMM_NBLK, 256, 0, stream>>>(row_start, csr, x0, deg, x1, s1, 1.0f);
    spmm_fused_kernel<<<SPMM_NBLK, 256, 0, stream>>>(row_start, csr, x1, deg, x2, s2, 1.0f);
    spmm_fused_kernel<<<SPMM_NBLK, 256, 0, stream>>>(row_start, csr, x2, deg, x3, s3, 7.81f);
    spmm_last_kernel<<<SPMM_NBLK, 256, 0, stream>>>(row_start, csr, x3, deg, x1, x2, x3,
                                                    s1, s2, s3, out, psum, psumsq, 45.28f);

    fold_kernel<<<DD, 256, 0, stream>>>(psum, psumsq, meanbuf, invstdb);
    normalize_kernel<<<NN * 32 / 256, 256, 0, stream>>>(out, meanbuf, invstdb);
}